// Round 1
// baseline (5158.501 us; speedup 1.0000x reference)
//
#include <hip/hip_runtime.h>

#define N_NODESC 10000
#define N_EDGESC 160000
#define ECHUNK   40000
#define NBLK_E   625                  // ECHUNK/64
#define NP       (N_NODESC*128)       // plane size (floats)
#define INV128   0.08838834764831845f // 1/sqrt(128)
#define INV_SQRT3C 0.5773502691896258f
#define SCALE_OUT 0.00390625f         // (1/sqrt(256))/16

__device__ __forceinline__ float silu_f(float x) {
  return x / (1.f + __expf(-x));
}

// ---------------- K1: node up-projections (5 GEMMs 10000x128 @ 128x128) ----
__global__ __launch_bounds__(256) void k_node_up(
    const float* __restrict__ nf,
    const float* __restrict__ Wsc,
    const float* __restrict__ Wu0,
    const float* __restrict__ Wu1,
    float* __restrict__ ws)  // planes: 0 NS, 1 SU, 2..4 VU_i
{
  __shared__ float sIn[64][132];
  __shared__ float sW[128][128];
  const int n0 = blockIdx.x * 64;
  const int which = blockIdx.y;  // 0 NS, 1 SU, 2..4 VU comp
  const float* W = (which == 0) ? Wsc : ((which == 1) ? Wu0 : Wu1);
  float* out = ws + (size_t)which * NP;

  for (int idx = threadIdx.x; idx < 128 * 32; idx += 256) {
    int r = idx >> 5, fc = (idx & 31) << 2;
    *(float4*)&sW[r][fc] = *(const float4*)&W[r * 128 + fc];
  }
  if (which < 2) {
    for (int idx = threadIdx.x; idx < 64 * 32; idx += 256) {
      int r = idx >> 5, fc = (idx & 31) << 2;
      int n = n0 + r;
      float4 v = {0.f, 0.f, 0.f, 0.f};
      if (n < N_NODESC) v = *(const float4*)&nf[(size_t)n * 512 + fc];
      *(float4*)&sIn[r][fc] = v;
    }
  } else {
    int comp = which - 2;
    for (int idx = threadIdx.x; idx < 64 * 128; idx += 256) {
      int r = idx >> 7, u = idx & 127;
      int n = n0 + r;
      sIn[r][u] = (n < N_NODESC) ? nf[(size_t)n * 512 + 128 + u * 3 + comp] : 0.f;
    }
  }
  __syncthreads();

  const int r0 = (threadIdx.x >> 4) * 4;
  const int c0 = (threadIdx.x & 15) * 8;
  float acc[4][8] = {};
  #pragma unroll 4
  for (int k = 0; k < 128; k++) {
    float a[4];
    #pragma unroll
    for (int j = 0; j < 4; j++) a[j] = sIn[r0 + j][k];
    float w[8];
    *(float4*)&w[0] = *(const float4*)&sW[k][c0];
    *(float4*)&w[4] = *(const float4*)&sW[k][c0 + 4];
    #pragma unroll
    for (int j = 0; j < 4; j++)
      #pragma unroll
      for (int c = 0; c < 8; c++) acc[j][c] += a[j] * w[c];
  }
  #pragma unroll
  for (int j = 0; j < 4; j++) {
    int n = n0 + r0 + j;
    if (n < N_NODESC) {
      float o[8];
      #pragma unroll
      for (int c = 0; c < 8; c++) o[c] = acc[j][c] * INV128;
      *(float4*)&out[(size_t)n * 128 + c0] = *(float4*)&o[0];
      *(float4*)&out[(size_t)n * 128 + c0 + 4] = *(float4*)&o[4];
    }
  }
}

// ---------------- K2: edge MLP layers 1+2 -> H ----------------------------
__global__ __launch_bounds__(256) void k_edge_mlp(
    const float* __restrict__ NS,
    const float* __restrict__ ef,
    const float* __restrict__ len,
    const int* __restrict__ eidx,
    const float* __restrict__ W1,
    const float* __restrict__ b1,
    const float* __restrict__ W2,
    const float* __restrict__ b2,
    float* __restrict__ H,
    int ebase)
{
  __shared__ float sA[64][132];
  __shared__ float sB[64][132];
  __shared__ float sH[64][132];
  __shared__ float sW[64][128];
  __shared__ float sWt[10][128];
  __shared__ float sEL[64][12];

  const int e0g = ebase + blockIdx.x * 64;
  for (int idx = threadIdx.x; idx < 64 * 32; idx += 256) {
    int r = idx >> 5, fc = (idx & 31) << 2;
    int e = e0g + r;
    int ns = eidx[e];
    int nr = eidx[N_EDGESC + e];
    *(float4*)&sA[r][fc] = *(const float4*)&NS[(size_t)ns * 128 + fc];
    *(float4*)&sB[r][fc] = *(const float4*)&NS[(size_t)nr * 128 + fc];
  }
  if (threadIdx.x < 64) {
    int r = threadIdx.x, e = e0g + r;
    #pragma unroll
    for (int j = 0; j < 8; j++) sEL[r][j] = ef[(size_t)e * 8 + j];
    sEL[r][8] = len[e];
  }
  for (int idx = threadIdx.x; idx < 10 * 128; idx += 256) {
    int r = idx >> 7, c = idx & 127;
    sWt[r][c] = (r < 9) ? W1[(256 + r) * 128 + c] : b1[c];
  }

  const int r0 = (threadIdx.x >> 4) * 4;
  const int c0 = (threadIdx.x & 15) * 8;
  float acc[4][8] = {};
  for (int kc = 0; kc < 4; kc++) {
    __syncthreads();
    for (int idx = threadIdx.x; idx < 64 * 32; idx += 256) {
      int r = idx >> 5, fc = (idx & 31) << 2;
      *(float4*)&sW[r][fc] = *(const float4*)&W1[(kc * 64 + r) * 128 + fc];
    }
    __syncthreads();
    const float (*sIn)[132] = (kc < 2) ? sA : sB;
    const int kof = (kc & 1) * 64;
    #pragma unroll 4
    for (int k = 0; k < 64; k++) {
      float a[4];
      #pragma unroll
      for (int j = 0; j < 4; j++) a[j] = sIn[r0 + j][kof + k];
      float w[8];
      *(float4*)&w[0] = *(const float4*)&sW[k][c0];
      *(float4*)&w[4] = *(const float4*)&sW[k][c0 + 4];
      #pragma unroll
      for (int j = 0; j < 4; j++)
        #pragma unroll
        for (int c = 0; c < 8; c++) acc[j][c] += a[j] * w[c];
    }
  }
  // tail (edge_feats, length) + bias + silu -> sH
  #pragma unroll
  for (int j = 0; j < 4; j++) {
    int r = r0 + j;
    #pragma unroll
    for (int c = 0; c < 8; c++) {
      float v = acc[j][c] + sWt[9][c0 + c];
      #pragma unroll
      for (int t = 0; t < 9; t++) v += sEL[r][t] * sWt[t][c0 + c];
      sH[r][c0 + c] = silu_f(v);
    }
  }
  // layer 2
  float acc2[4][8] = {};
  for (int kc = 0; kc < 2; kc++) {
    __syncthreads();
    for (int idx = threadIdx.x; idx < 64 * 32; idx += 256) {
      int r = idx >> 5, fc = (idx & 31) << 2;
      *(float4*)&sW[r][fc] = *(const float4*)&W2[(kc * 64 + r) * 128 + fc];
    }
    __syncthreads();
    const int kof = kc * 64;
    #pragma unroll 4
    for (int k = 0; k < 64; k++) {
      float a[4];
      #pragma unroll
      for (int j = 0; j < 4; j++) a[j] = sH[r0 + j][kof + k];
      float w[8];
      *(float4*)&w[0] = *(const float4*)&sW[k][c0];
      *(float4*)&w[4] = *(const float4*)&sW[k][c0 + 4];
      #pragma unroll
      for (int j = 0; j < 4; j++)
        #pragma unroll
        for (int c = 0; c < 8; c++) acc2[j][c] += a[j] * w[c];
    }
  }
  const int elb = blockIdx.x * 64;
  #pragma unroll
  for (int j = 0; j < 4; j++) {
    float o[8];
    #pragma unroll
    for (int c = 0; c < 8; c++) o[c] = silu_f(acc2[j][c] + b2[c0 + c]);
    size_t base = (size_t)(elb + r0 + j) * 128 + c0;
    *(float4*)&H[base] = *(float4*)&o[0];
    *(float4*)&H[base + 4] = *(float4*)&o[4];
  }
}

// ---------------- K3: layer 3 (per col-chunk) + messages + atomic scatter --
__global__ __launch_bounds__(256) void k_edge_msg(
    const float* __restrict__ H,
    const float* __restrict__ SU,
    const float* __restrict__ VU,   // 3 planes
    const float* __restrict__ ea,   // edge_attrs (E,4)
    const int* __restrict__ eidx,
    const float* __restrict__ W3,
    float* __restrict__ MSG,        // 8 planes: ms0, ms1, mva0..2, mvb0..2
    int ebase)
{
  __shared__ float sH[64][132];
  __shared__ float sSe[64][132];
  __shared__ float sW[64][128];
  __shared__ float sY[64][4];
  __shared__ int sSnd[64], sRcv[64];

  const int e0g = ebase + blockIdx.x * 64;
  const int elb = blockIdx.x * 64;
  for (int idx = threadIdx.x; idx < 64 * 32; idx += 256) {
    int r = idx >> 5, fc = (idx & 31) << 2;
    int e = e0g + r;
    int ns = eidx[e];
    *(float4*)&sH[r][fc] = *(const float4*)&H[(size_t)(elb + r) * 128 + fc];
    *(float4*)&sSe[r][fc] = *(const float4*)&SU[(size_t)ns * 128 + fc];
  }
  if (threadIdx.x < 64) {
    int r = threadIdx.x, e = e0g + r;
    sSnd[r] = eidx[e];
    sRcv[r] = eidx[N_EDGESC + e];
    *(float4*)&sY[r][0] = *(const float4*)&ea[(size_t)e * 4];
  }
  const int r0 = (threadIdx.x >> 4) * 4;
  const int c0 = (threadIdx.x & 15) * 8;

  for (int cb = 0; cb < 4; cb++) {
    float acc[4][8] = {};
    for (int kc = 0; kc < 2; kc++) {
      __syncthreads();
      for (int idx = threadIdx.x; idx < 64 * 32; idx += 256) {
        int r = idx >> 5, fc = (idx & 31) << 2;
        *(float4*)&sW[r][fc] =
            *(const float4*)&W3[(size_t)(kc * 64 + r) * 512 + cb * 128 + fc];
      }
      __syncthreads();
      const int kof = kc * 64;
      #pragma unroll 4
      for (int k = 0; k < 64; k++) {
        float a[4];
        #pragma unroll
        for (int j = 0; j < 4; j++) a[j] = sH[r0 + j][kof + k];
        float w[8];
        *(float4*)&w[0] = *(const float4*)&sW[k][c0];
        *(float4*)&w[4] = *(const float4*)&sW[k][c0 + 4];
        #pragma unroll
        for (int j = 0; j < 4; j++)
          #pragma unroll
          for (int c = 0; c < 8; c++) acc[j][c] += a[j] * w[c];
      }
    }
    // message emit for this chunk
    #pragma unroll
    for (int j = 0; j < 4; j++) {
      int r = r0 + j;
      int snd = sSnd[r], rcv = sRcv[r];
      float y0 = sY[r][0];
      float y1a = sY[r][1], y1b = sY[r][2], y1c = sY[r][3];
      size_t sbase = (size_t)snd * 128 + c0;
      size_t rbase = (size_t)rcv * 128 + c0;
      if (cb == 0) {
        #pragma unroll
        for (int c = 0; c < 8; c++) {
          float val = acc[j][c] * sSe[r][c0 + c] * y0;
          atomicAdd(&MSG[rbase + c], val);
        }
      } else if (cb == 1) {
        #pragma unroll
        for (int c = 0; c < 8; c++) {
          float t = acc[j][c] * sSe[r][c0 + c];
          atomicAdd(&MSG[2 * (size_t)NP + rbase + c], t * y1a);
          atomicAdd(&MSG[3 * (size_t)NP + rbase + c], t * y1b);
          atomicAdd(&MSG[4 * (size_t)NP + rbase + c], t * y1c);
        }
      } else if (cb == 2) {
        #pragma unroll
        for (int c = 0; c < 8; c++) {
          float t = acc[j][c] * y0;
          atomicAdd(&MSG[5 * (size_t)NP + rbase + c], t * VU[0 * (size_t)NP + sbase + c]);
          atomicAdd(&MSG[6 * (size_t)NP + rbase + c], t * VU[1 * (size_t)NP + sbase + c]);
          atomicAdd(&MSG[7 * (size_t)NP + rbase + c], t * VU[2 * (size_t)NP + sbase + c]);
        }
      } else {
        #pragma unroll
        for (int c = 0; c < 8; c++) {
          float dot = VU[0 * (size_t)NP + sbase + c] * y1a
                    + VU[1 * (size_t)NP + sbase + c] * y1b
                    + VU[2 * (size_t)NP + sbase + c] * y1c;
          float val = acc[j][c] * dot * INV_SQRT3C;
          atomicAdd(&MSG[1 * (size_t)NP + rbase + c], val);
        }
      }
    }
  }
}

// ---------------- K4: output GEMMs + interleaved store ---------------------
__global__ __launch_bounds__(256) void k_out(
    const float* __restrict__ MSG,
    const float* __restrict__ Wo0,
    const float* __restrict__ Wo1,
    float* __restrict__ out)
{
  __shared__ float sA[64][132];
  __shared__ float sB[64][132];
  __shared__ float sW[64][128];
  const int n0 = blockIdx.x * 64;
  const int y = blockIdx.y;  // 0 scalar, 1..3 vector comp
  const float* W = (y == 0) ? Wo0 : Wo1;
  const float* pA = MSG + (size_t)((y == 0) ? 0 : (1 + y)) * NP;  // ms0 | mva_i
  const float* pB = MSG + (size_t)((y == 0) ? 1 : (4 + y)) * NP;  // ms1 | mvb_i

  for (int idx = threadIdx.x; idx < 64 * 32; idx += 256) {
    int r = idx >> 5, fc = (idx & 31) << 2;
    int n = n0 + r;
    float4 va = {0.f, 0.f, 0.f, 0.f}, vb = {0.f, 0.f, 0.f, 0.f};
    if (n < N_NODESC) {
      va = *(const float4*)&pA[(size_t)n * 128 + fc];
      vb = *(const float4*)&pB[(size_t)n * 128 + fc];
    }
    *(float4*)&sA[r][fc] = va;
    *(float4*)&sB[r][fc] = vb;
  }
  const int r0 = (threadIdx.x >> 4) * 4;
  const int c0 = (threadIdx.x & 15) * 8;
  float acc[4][8] = {};
  for (int kc = 0; kc < 4; kc++) {
    __syncthreads();
    for (int idx = threadIdx.x; idx < 64 * 32; idx += 256) {
      int r = idx >> 5, fc = (idx & 31) << 2;
      *(float4*)&sW[r][fc] = *(const float4*)&W[(kc * 64 + r) * 128 + fc];
    }
    __syncthreads();
    const float (*sIn)[132] = (kc < 2) ? sA : sB;
    const int kof = (kc & 1) * 64;
    #pragma unroll 4
    for (int k = 0; k < 64; k++) {
      float a[4];
      #pragma unroll
      for (int j = 0; j < 4; j++) a[j] = sIn[r0 + j][kof + k];
      float w[8];
      *(float4*)&w[0] = *(const float4*)&sW[k][c0];
      *(float4*)&w[4] = *(const float4*)&sW[k][c0 + 4];
      #pragma unroll
      for (int j = 0; j < 4; j++)
        #pragma unroll
        for (int c = 0; c < 8; c++) acc[j][c] += a[j] * w[c];
    }
  }
  #pragma unroll
  for (int j = 0; j < 4; j++) {
    int n = n0 + r0 + j;
    if (n < N_NODESC) {
      #pragma unroll
      for (int c = 0; c < 8; c++)
        out[(size_t)n * 512 + (size_t)(c0 + c) * 4 + y] = acc[j][c] * SCALE_OUT;
    }
  }
}

extern "C" void kernel_launch(void* const* d_in, const int* in_sizes, int n_in,
                              void* d_out, int out_size, void* d_ws, size_t ws_size,
                              hipStream_t stream) {
  const float* nf  = (const float*)d_in[0];
  const float* ea  = (const float*)d_in[1];
  const float* ef  = (const float*)d_in[2];
  const float* len = (const float*)d_in[3];
  const int*   ei  = (const int*)d_in[4];
  const float* Wsc = (const float*)d_in[5];
  const float* Wu0 = (const float*)d_in[6];
  const float* Wu1 = (const float*)d_in[7];
  const float* W1  = (const float*)d_in[8];
  const float* b1  = (const float*)d_in[9];
  const float* W2  = (const float*)d_in[10];
  const float* b2  = (const float*)d_in[11];
  const float* W3  = (const float*)d_in[12];
  const float* Wo0 = (const float*)d_in[13];
  const float* Wo1 = (const float*)d_in[14];
  float* out = (float*)d_out;
  float* ws  = (float*)d_ws;

  float* NS  = ws;                       // 1 plane
  float* SU  = NS + (size_t)NP;          // 1 plane
  float* VU  = SU + (size_t)NP;          // 3 planes
  float* MSG = VU + 3 * (size_t)NP;      // 8 planes
  float* H   = MSG + 8 * (size_t)NP;     // ECHUNK*128

  hipMemsetAsync(MSG, 0, 8 * (size_t)NP * sizeof(float), stream);
  k_node_up<<<dim3(157, 5), 256, 0, stream>>>(nf, Wsc, Wu0, Wu1, ws);
  for (int ch = 0; ch < 4; ch++) {
    int ebase = ch * ECHUNK;
    k_edge_mlp<<<NBLK_E, 256, 0, stream>>>(NS, ef, len, ei, W1, b1, W2, b2, H, ebase);
    k_edge_msg<<<NBLK_E, 256, 0, stream>>>(H, SU, VU, ea, ei, W3, MSG, ebase);
  }
  k_out<<<dim3(157, 4), 256, 0, stream>>>(MSG, Wo0, Wo1, out);
}

// Round 2
// 1884.146 us; speedup vs baseline: 2.7378x; 2.7378x over previous
//
#include <hip/hip_runtime.h>

#define N_NODESC 10000
#define N_EDGESC 160000
#define ECHUNK   16000
#define NCHUNK   10
#define CBLK     250                  // blocks per chunk (ECHUNK/64)
#define NBLK_TOT 2500                 // CBLK*NCHUNK
#define NP       (N_NODESC*128)       // plane size (floats)
#define INV128   0.08838834764831845f // 1/sqrt(128)
#define INV_SQRT3C 0.5773502691896258f
#define SCALE_OUT 0.00390625f         // (1/sqrt(256))/16

__device__ __forceinline__ float silu_f(float x) {
  return x / (1.f + __expf(-x));
}

// ---------------- CSR build ------------------------------------------------
__global__ __launch_bounds__(256) void k_hist(const int* __restrict__ eidx,
                                              int* __restrict__ deg) {
  int e = blockIdx.x * 256 + threadIdx.x;
  if (e < N_EDGESC) atomicAdd(&deg[eidx[N_EDGESC + e]], 1);
}

__global__ __launch_bounds__(1024) void k_scan(const int* __restrict__ deg,
                                               int* __restrict__ row_start) {
  __shared__ int buf[1024];
  __shared__ int sc;
  if (threadIdx.x == 0) sc = 0;
  __syncthreads();
  for (int base = 0; base < N_NODESC; base += 1024) {
    int i = base + threadIdx.x;
    int d = (i < N_NODESC) ? deg[i] : 0;
    int v = d;
    buf[threadIdx.x] = v;
    __syncthreads();
    for (int off = 1; off < 1024; off <<= 1) {
      int t = (threadIdx.x >= off) ? buf[threadIdx.x - off] : 0;
      __syncthreads();
      v += t;
      buf[threadIdx.x] = v;
      __syncthreads();
    }
    if (i < N_NODESC) row_start[i] = sc + v - d;
    int tot = buf[1023];
    __syncthreads();
    if (threadIdx.x == 0) sc += tot;
    __syncthreads();
  }
  if (threadIdx.x == 0) row_start[N_NODESC] = sc;
}

__global__ __launch_bounds__(256) void k_scatter(const int* __restrict__ eidx,
                                                 const int* __restrict__ row_start,
                                                 int* __restrict__ cursor,
                                                 int* __restrict__ perm) {
  int e = blockIdx.x * 256 + threadIdx.x;
  if (e < N_EDGESC) {
    int r = eidx[N_EDGESC + e];
    int pos = row_start[r] + atomicAdd(&cursor[r], 1);
    perm[pos] = e;
  }
}

// deterministic order: sort each node's segment by edge id (insertion sort)
__global__ __launch_bounds__(256) void k_sortseg(int* __restrict__ perm,
                                                 const int* __restrict__ row_start) {
  int n = blockIdx.x * 256 + threadIdx.x;
  if (n >= N_NODESC) return;
  int s = row_start[n], e = row_start[n + 1];
  for (int i = s + 1; i < e; i++) {
    int key = perm[i];
    int j = i - 1;
    while (j >= s && perm[j] > key) { perm[j + 1] = perm[j]; j--; }
    perm[j + 1] = key;
  }
}

// ---------------- K1: node up-projections (unchanged) ----------------------
__global__ __launch_bounds__(256) void k_node_up(
    const float* __restrict__ nf,
    const float* __restrict__ Wsc,
    const float* __restrict__ Wu0,
    const float* __restrict__ Wu1,
    float* __restrict__ ws)  // planes: 0 NS, 1 SU, 2..4 VU_i
{
  __shared__ float sIn[64][132];
  __shared__ float sW[128][128];
  const int n0 = blockIdx.x * 64;
  const int which = blockIdx.y;
  const float* W = (which == 0) ? Wsc : ((which == 1) ? Wu0 : Wu1);
  float* out = ws + (size_t)which * NP;

  for (int idx = threadIdx.x; idx < 128 * 32; idx += 256) {
    int r = idx >> 5, fc = (idx & 31) << 2;
    *(float4*)&sW[r][fc] = *(const float4*)&W[r * 128 + fc];
  }
  if (which < 2) {
    for (int idx = threadIdx.x; idx < 64 * 32; idx += 256) {
      int r = idx >> 5, fc = (idx & 31) << 2;
      int n = n0 + r;
      float4 v = {0.f, 0.f, 0.f, 0.f};
      if (n < N_NODESC) v = *(const float4*)&nf[(size_t)n * 512 + fc];
      *(float4*)&sIn[r][fc] = v;
    }
  } else {
    int comp = which - 2;
    for (int idx = threadIdx.x; idx < 64 * 128; idx += 256) {
      int r = idx >> 7, u = idx & 127;
      int n = n0 + r;
      sIn[r][u] = (n < N_NODESC) ? nf[(size_t)n * 512 + 128 + u * 3 + comp] : 0.f;
    }
  }
  __syncthreads();

  const int r0 = (threadIdx.x >> 4) * 4;
  const int c0 = (threadIdx.x & 15) * 8;
  float acc[4][8] = {};
  #pragma unroll 4
  for (int k = 0; k < 128; k++) {
    float a[4];
    #pragma unroll
    for (int j = 0; j < 4; j++) a[j] = sIn[r0 + j][k];
    float w[8];
    *(float4*)&w[0] = *(const float4*)&sW[k][c0];
    *(float4*)&w[4] = *(const float4*)&sW[k][c0 + 4];
    #pragma unroll
    for (int j = 0; j < 4; j++)
      #pragma unroll
      for (int c = 0; c < 8; c++) acc[j][c] += a[j] * w[c];
  }
  #pragma unroll
  for (int j = 0; j < 4; j++) {
    int n = n0 + r0 + j;
    if (n < N_NODESC) {
      float o[8];
      #pragma unroll
      for (int c = 0; c < 8; c++) o[c] = acc[j][c] * INV128;
      *(float4*)&out[(size_t)n * 128 + c0] = *(float4*)&o[0];
      *(float4*)&out[(size_t)n * 128 + c0 + 4] = *(float4*)&o[4];
    }
  }
}

// ---------------- K2: edge MLP layers 1+2 (sorted order) -------------------
__global__ __launch_bounds__(256) void k_edge_mlp_s(
    const float* __restrict__ NS,
    const float* __restrict__ ef,
    const float* __restrict__ len,
    const int* __restrict__ eidx,
    const int* __restrict__ perm,
    const float* __restrict__ W1,
    const float* __restrict__ b1,
    const float* __restrict__ W2,
    const float* __restrict__ b2,
    float* __restrict__ H,
    int sbase)
{
  __shared__ float sA[64][132];
  __shared__ float sW[64][132];
  __shared__ float sT[10][128];
  __shared__ float sEL[64][12];
  __shared__ int sSnd[64], sRcv[64];

  const int j0 = sbase + blockIdx.x * 64;
  if (threadIdx.x < 64) {
    int r = threadIdx.x;
    int e = perm[j0 + r];
    sSnd[r] = eidx[e];
    sRcv[r] = eidx[N_EDGESC + e];
    #pragma unroll
    for (int q = 0; q < 8; q++) sEL[r][q] = ef[(size_t)e * 8 + q];
    sEL[r][8] = len[e];
  }
  for (int idx = threadIdx.x; idx < 10 * 128; idx += 256) {
    int r = idx >> 7, c = idx & 127;
    sT[r][c] = (r < 9) ? W1[(256 + r) * 128 + c] : b1[c];
  }

  const int r0 = (threadIdx.x >> 4) * 4;
  const int c0 = (threadIdx.x & 15) * 8;
  float acc[4][8] = {};
  for (int half = 0; half < 2; half++) {
    __syncthreads();  // meta ready (half 0) / previous GEMM done (half 1)
    for (int idx = threadIdx.x; idx < 64 * 32; idx += 256) {
      int r = idx >> 5, fc = (idx & 31) << 2;
      int n = half ? sRcv[r] : sSnd[r];
      *(float4*)&sA[r][fc] = *(const float4*)&NS[(size_t)n * 128 + fc];
    }
    for (int kc = 0; kc < 2; kc++) {
      __syncthreads();
      for (int idx = threadIdx.x; idx < 64 * 32; idx += 256) {
        int r = idx >> 5, fc = (idx & 31) << 2;
        *(float4*)&sW[r][fc] = *(const float4*)&W1[((half * 2 + kc) * 64 + r) * 128 + fc];
      }
      __syncthreads();
      const int kof = kc * 64;
      #pragma unroll 4
      for (int k = 0; k < 64; k++) {
        float a[4];
        #pragma unroll
        for (int j = 0; j < 4; j++) a[j] = sA[r0 + j][kof + k];
        float w[8];
        *(float4*)&w[0] = *(const float4*)&sW[k][c0];
        *(float4*)&w[4] = *(const float4*)&sW[k][c0 + 4];
        #pragma unroll
        for (int j = 0; j < 4; j++)
          #pragma unroll
          for (int c = 0; c < 8; c++) acc[j][c] += a[j] * w[c];
      }
      __syncthreads();
    }
  }
  // tail + bias + silu -> h written into sA (dead)
  #pragma unroll
  for (int j = 0; j < 4; j++) {
    int r = r0 + j;
    #pragma unroll
    for (int c = 0; c < 8; c++) {
      float v = acc[j][c] + sT[9][c0 + c];
      #pragma unroll
      for (int t = 0; t < 9; t++) v += sEL[r][t] * sT[t][c0 + c];
      sA[r][c0 + c] = silu_f(v);
    }
  }
  // layer 2
  float acc2[4][8] = {};
  for (int kc = 0; kc < 2; kc++) {
    __syncthreads();
    for (int idx = threadIdx.x; idx < 64 * 32; idx += 256) {
      int r = idx >> 5, fc = (idx & 31) << 2;
      *(float4*)&sW[r][fc] = *(const float4*)&W2[(kc * 64 + r) * 128 + fc];
    }
    __syncthreads();
    const int kof = kc * 64;
    #pragma unroll 4
    for (int k = 0; k < 64; k++) {
      float a[4];
      #pragma unroll
      for (int j = 0; j < 4; j++) a[j] = sA[r0 + j][kof + k];
      float w[8];
      *(float4*)&w[0] = *(const float4*)&sW[k][c0];
      *(float4*)&w[4] = *(const float4*)&sW[k][c0 + 4];
      #pragma unroll
      for (int j = 0; j < 4; j++)
        #pragma unroll
        for (int c = 0; c < 8; c++) acc2[j][c] += a[j] * w[c];
    }
  }
  const int elb = blockIdx.x * 64;
  #pragma unroll
  for (int j = 0; j < 4; j++) {
    float o[8];
    #pragma unroll
    for (int c = 0; c < 8; c++) o[c] = silu_f(acc2[j][c] + b2[c0 + c]);
    size_t base = (size_t)(elb + r0 + j) * 128 + c0;
    *(float4*)&H[base] = *(float4*)&o[0];
    *(float4*)&H[base + 4] = *(float4*)&o[4];
  }
}

// ---------------- K3: layer 3 + messages + segmented reduce (no atomics) ---
__global__ __launch_bounds__(256) void k_edge_msg_s(
    const float* __restrict__ H,
    const float* __restrict__ SU,
    const float* __restrict__ VU,   // 3 planes
    const float* __restrict__ ea,
    const int* __restrict__ eidx,
    const int* __restrict__ perm,
    const int* __restrict__ row_start,
    const float* __restrict__ W3,
    float* __restrict__ MSG,        // 8 planes: ms0, ms1, mva0..2, mvb0..2
    float* __restrict__ CONT,       // [NBLK_TOT][1024]
    int chunk)
{
  __shared__ float sH[64][132];
  __shared__ float sWM[64][132];    // W3 tile during GEMM; message transpose after
  __shared__ float sY4[64][4];
  __shared__ int sSnd[64], sRcv[64];
  __shared__ int sContFirst;

  const int gblk = chunk * CBLK + blockIdx.x;
  const int j0 = gblk * 64;
  if (threadIdx.x < 64) {
    int r = threadIdx.x;
    int e = perm[j0 + r];
    sSnd[r] = eidx[e];
    sRcv[r] = eidx[N_EDGESC + e];
    *(float4*)&sY4[r][0] = *(const float4*)&ea[(size_t)e * 4];
    if (r == 0) sContFirst = (row_start[eidx[N_EDGESC + e]] != j0) ? 1 : 0;
  }
  for (int idx = threadIdx.x; idx < 64 * 32; idx += 256) {
    int r = idx >> 5, fc = (idx & 31) << 2;
    *(float4*)&sH[r][fc] = *(const float4*)&H[(size_t)(blockIdx.x * 64 + r) * 128 + fc];
  }
  __syncthreads();

  const int r0 = (threadIdx.x >> 4) * 4;
  const int c0 = (threadIdx.x & 15) * 8;
  const int cid = threadIdx.x;
  const bool contF = (sContFirst != 0);

  int snd[4];
  float y0r[4], y1r[4][3];
  #pragma unroll
  for (int j = 0; j < 4; j++) {
    snd[j] = sSnd[r0 + j];
    y0r[j] = sY4[r0 + j][0];
    #pragma unroll
    for (int i = 0; i < 3; i++) y1r[j][i] = sY4[r0 + j][1 + i];
  }
  float seR[4][8];
  #pragma unroll
  for (int j = 0; j < 4; j++)
    #pragma unroll
    for (int c = 0; c < 8; c++)
      seR[j][c] = SU[(size_t)snd[j] * 128 + c0 + c];

  for (int cb = 0; cb < 4; cb++) {
    float acc[4][8] = {};
    for (int kc = 0; kc < 2; kc++) {
      __syncthreads();
      for (int idx = threadIdx.x; idx < 64 * 32; idx += 256) {
        int r = idx >> 5, fc = (idx & 31) << 2;
        *(float4*)&sWM[r][fc] =
            *(const float4*)&W3[(size_t)(kc * 64 + r) * 512 + cb * 128 + fc];
      }
      __syncthreads();
      const int kof = kc * 64;
      #pragma unroll 4
      for (int k = 0; k < 64; k++) {
        float a[4];
        #pragma unroll
        for (int j = 0; j < 4; j++) a[j] = sH[r0 + j][kof + k];
        float w[8];
        *(float4*)&w[0] = *(const float4*)&sWM[k][c0];
        *(float4*)&w[4] = *(const float4*)&sWM[k][c0 + 4];
        #pragma unroll
        for (int j = 0; j < 4; j++)
          #pragma unroll
          for (int c = 0; c < 8; c++) acc[j][c] += a[j] * w[c];
      }
    }
    const int npl = (cb == 0 || cb == 3) ? 1 : 3;
    for (int pi = 0; pi < npl; pi++) {
      int p;
      __syncthreads();  // sWM free (GEMM done / previous reduce done)
      #pragma unroll
      for (int j = 0; j < 4; j++) {
        #pragma unroll
        for (int c = 0; c < 8; c++) {
          float m;
          if (cb == 0) {
            m = acc[j][c] * seR[j][c] * y0r[j];
          } else if (cb == 1) {
            m = acc[j][c] * seR[j][c] * y1r[j][pi];
          } else if (cb == 2) {
            float ve = VU[(size_t)pi * NP + (size_t)snd[j] * 128 + c0 + c];
            m = acc[j][c] * y0r[j] * ve;
          } else {
            float dot = VU[(size_t)snd[j] * 128 + c0 + c] * y1r[j][0]
                      + VU[(size_t)NP + (size_t)snd[j] * 128 + c0 + c] * y1r[j][1]
                      + VU[2 * (size_t)NP + (size_t)snd[j] * 128 + c0 + c] * y1r[j][2];
            m = acc[j][c] * dot * INV_SQRT3C;
          }
          sWM[r0 + j][c0 + c] = m;
        }
      }
      p = (cb == 0) ? 0 : ((cb == 3) ? 1 : ((cb == 1) ? 2 + pi : 5 + pi));
      __syncthreads();
      if (cid < 128) {
        float sum = 0.f;
        int prev = sRcv[0];
        int segl = 0;
        for (int e2 = 0; e2 < 64; e2++) {
          int rv = sRcv[e2];
          if (rv != prev) {
            if (segl == 0 && contF)
              CONT[(size_t)gblk * 1024 + p * 128 + cid] = sum;
            else
              MSG[(size_t)p * NP + (size_t)prev * 128 + cid] = sum;
            prev = rv; segl = e2; sum = 0.f;
          }
          sum += sWM[e2][cid];
        }
        if (segl == 0 && contF)
          CONT[(size_t)gblk * 1024 + p * 128 + cid] = sum;
        else
          MSG[(size_t)p * NP + (size_t)prev * 128 + cid] = sum;
      }
    }
  }
}

// ---------------- fixup: add continuation partials into MSG ----------------
__global__ __launch_bounds__(256) void k_fixup(float* __restrict__ MSG,
                                               const float* __restrict__ CONT,
                                               const int* __restrict__ row_start) {
  int t = blockIdx.x * 256 + threadIdx.x;
  int n = t >> 5;
  int c4 = (t & 31) * 4;
  if (n >= N_NODESC) return;
  int s = row_start[n], e = row_start[n + 1];
  if (e <= s) return;
  int b0 = s >> 6, b1 = (e - 1) >> 6;
  if (b1 <= b0) return;
  for (int p = 0; p < 8; p++) {
    float4 v = *(float4*)&MSG[(size_t)p * NP + (size_t)n * 128 + c4];
    for (int b = b0 + 1; b <= b1; b++) {
      const float4 u = *(const float4*)&CONT[(size_t)b * 1024 + p * 128 + c4];
      v.x += u.x; v.y += u.y; v.z += u.z; v.w += u.w;
    }
    *(float4*)&MSG[(size_t)p * NP + (size_t)n * 128 + c4] = v;
  }
}

// ---------------- K4: output GEMMs (unchanged) ------------------------------
__global__ __launch_bounds__(256) void k_out(
    const float* __restrict__ MSG,
    const float* __restrict__ Wo0,
    const float* __restrict__ Wo1,
    float* __restrict__ out)
{
  __shared__ float sA[64][132];
  __shared__ float sB[64][132];
  __shared__ float sW[64][128];
  const int n0 = blockIdx.x * 64;
  const int y = blockIdx.y;
  const float* W = (y == 0) ? Wo0 : Wo1;
  const float* pA = MSG + (size_t)((y == 0) ? 0 : (1 + y)) * NP;
  const float* pB = MSG + (size_t)((y == 0) ? 1 : (4 + y)) * NP;

  for (int idx = threadIdx.x; idx < 64 * 32; idx += 256) {
    int r = idx >> 5, fc = (idx & 31) << 2;
    int n = n0 + r;
    float4 va = {0.f, 0.f, 0.f, 0.f}, vb = {0.f, 0.f, 0.f, 0.f};
    if (n < N_NODESC) {
      va = *(const float4*)&pA[(size_t)n * 128 + fc];
      vb = *(const float4*)&pB[(size_t)n * 128 + fc];
    }
    *(float4*)&sA[r][fc] = va;
    *(float4*)&sB[r][fc] = vb;
  }
  const int r0 = (threadIdx.x >> 4) * 4;
  const int c0 = (threadIdx.x & 15) * 8;
  float acc[4][8] = {};
  for (int kc = 0; kc < 4; kc++) {
    __syncthreads();
    for (int idx = threadIdx.x; idx < 64 * 32; idx += 256) {
      int r = idx >> 5, fc = (idx & 31) << 2;
      *(float4*)&sW[r][fc] = *(const float4*)&W[(kc * 64 + r) * 128 + fc];
    }
    __syncthreads();
    const float (*sIn)[132] = (kc < 2) ? sA : sB;
    const int kof = (kc & 1) * 64;
    #pragma unroll 4
    for (int k = 0; k < 64; k++) {
      float a[4];
      #pragma unroll
      for (int j = 0; j < 4; j++) a[j] = sIn[r0 + j][kof + k];
      float w[8];
      *(float4*)&w[0] = *(const float4*)&sW[k][c0];
      *(float4*)&w[4] = *(const float4*)&sW[k][c0 + 4];
      #pragma unroll
      for (int j = 0; j < 4; j++)
        #pragma unroll
        for (int c = 0; c < 8; c++) acc[j][c] += a[j] * w[c];
    }
  }
  #pragma unroll
  for (int j = 0; j < 4; j++) {
    int n = n0 + r0 + j;
    if (n < N_NODESC) {
      #pragma unroll
      for (int c = 0; c < 8; c++)
        out[(size_t)n * 512 + (size_t)(c0 + c) * 4 + y] = acc[j][c] * SCALE_OUT;
    }
  }
}

extern "C" void kernel_launch(void* const* d_in, const int* in_sizes, int n_in,
                              void* d_out, int out_size, void* d_ws, size_t ws_size,
                              hipStream_t stream) {
  const float* nf  = (const float*)d_in[0];
  const float* ea  = (const float*)d_in[1];
  const float* ef  = (const float*)d_in[2];
  const float* len = (const float*)d_in[3];
  const int*   ei  = (const int*)d_in[4];
  const float* Wsc = (const float*)d_in[5];
  const float* Wu0 = (const float*)d_in[6];
  const float* Wu1 = (const float*)d_in[7];
  const float* W1  = (const float*)d_in[8];
  const float* b1  = (const float*)d_in[9];
  const float* W2  = (const float*)d_in[10];
  const float* b2  = (const float*)d_in[11];
  const float* W3  = (const float*)d_in[12];
  const float* Wo0 = (const float*)d_in[13];
  const float* Wo1 = (const float*)d_in[14];
  float* out = (float*)d_out;
  float* ws  = (float*)d_ws;

  const size_t NPs = (size_t)NP;
  float* NS   = ws;                            // 1 plane
  float* SU   = ws + NPs;                      // 1 plane
  float* VU   = ws + 2 * NPs;                  // 3 planes
  float* MSG  = ws + 5 * NPs;                  // 8 planes
  float* H    = ws + 13 * NPs;                 // ECHUNK*128
  float* CONT = H + (size_t)ECHUNK * 128;      // NBLK_TOT*1024
  int* perm      = (int*)(CONT + (size_t)NBLK_TOT * 1024);
  int* deg       = perm + N_EDGESC;
  int* cursor    = deg + N_NODESC;
  int* row_start = cursor + N_NODESC;          // N_NODESC+1 ints

  hipMemsetAsync(deg, 0, N_NODESC * sizeof(int), stream);
  hipMemsetAsync(cursor, 0, N_NODESC * sizeof(int), stream);
  hipMemsetAsync(MSG, 0, 8 * NPs * sizeof(float), stream);

  k_hist<<<(N_EDGESC + 255) / 256, 256, 0, stream>>>(ei, deg);
  k_scan<<<1, 1024, 0, stream>>>(deg, row_start);
  k_scatter<<<(N_EDGESC + 255) / 256, 256, 0, stream>>>(ei, row_start, cursor, perm);
  k_sortseg<<<(N_NODESC + 255) / 256, 256, 0, stream>>>(perm, row_start);

  k_node_up<<<dim3(157, 5), 256, 0, stream>>>(nf, Wsc, Wu0, Wu1, ws);

  for (int ch = 0; ch < NCHUNK; ch++) {
    k_edge_mlp_s<<<CBLK, 256, 0, stream>>>(NS, ef, len, ei, perm, W1, b1, W2, b2,
                                           H, ch * ECHUNK);
    k_edge_msg_s<<<CBLK, 256, 0, stream>>>(H, SU, VU, ea, ei, perm, row_start, W3,
                                           MSG, CONT, ch);
  }
  k_fixup<<<(N_NODESC * 32 + 255) / 256, 256, 0, stream>>>(MSG, CONT, row_start);
  k_out<<<dim3(157, 4), 256, 0, stream>>>(MSG, Wo0, Wo1, out);
}

// Round 3
// 1177.715 us; speedup vs baseline: 4.3801x; 1.5998x over previous
//
#include <hip/hip_runtime.h>

#define N_NODESC 10000
#define N_EDGESC 160000
#define NBLK_TOT 2500                 // N_EDGESC/64
#define NP       (N_NODESC*128)       // plane size (floats)
#define INV128   0.08838834764831845f // 1/sqrt(128)
#define INV_SQRT3C 0.5773502691896258f
#define SCALE_OUT 0.00390625f         // (1/sqrt(256))/16

__device__ __forceinline__ float silu_f(float x) {
  return x / (1.f + __expf(-x));
}

// ---------------- CSR build ------------------------------------------------
__global__ __launch_bounds__(256) void k_hist(const int* __restrict__ eidx,
                                              int* __restrict__ deg) {
  int e = blockIdx.x * 256 + threadIdx.x;
  if (e < N_EDGESC) atomicAdd(&deg[eidx[N_EDGESC + e]], 1);
}

__global__ __launch_bounds__(1024) void k_scan(const int* __restrict__ deg,
                                               int* __restrict__ row_start) {
  __shared__ int buf[1024];
  __shared__ int sc;
  if (threadIdx.x == 0) sc = 0;
  __syncthreads();
  for (int base = 0; base < N_NODESC; base += 1024) {
    int i = base + threadIdx.x;
    int d = (i < N_NODESC) ? deg[i] : 0;
    int v = d;
    buf[threadIdx.x] = v;
    __syncthreads();
    for (int off = 1; off < 1024; off <<= 1) {
      int t = (threadIdx.x >= off) ? buf[threadIdx.x - off] : 0;
      __syncthreads();
      v += t;
      buf[threadIdx.x] = v;
      __syncthreads();
    }
    if (i < N_NODESC) row_start[i] = sc + v - d;
    int tot = buf[1023];
    __syncthreads();
    if (threadIdx.x == 0) sc += tot;
    __syncthreads();
  }
  if (threadIdx.x == 0) row_start[N_NODESC] = sc;
}

__global__ __launch_bounds__(256) void k_scatter(const int* __restrict__ eidx,
                                                 const int* __restrict__ row_start,
                                                 int* __restrict__ cursor,
                                                 int* __restrict__ perm) {
  int e = blockIdx.x * 256 + threadIdx.x;
  if (e < N_EDGESC) {
    int r = eidx[N_EDGESC + e];
    int pos = row_start[r] + atomicAdd(&cursor[r], 1);
    perm[pos] = e;
  }
}

// deterministic order: sort each node's segment by edge id (insertion sort)
__global__ __launch_bounds__(256) void k_sortseg(int* __restrict__ perm,
                                                 const int* __restrict__ row_start) {
  int n = blockIdx.x * 256 + threadIdx.x;
  if (n >= N_NODESC) return;
  int s = row_start[n], e = row_start[n + 1];
  for (int i = s + 1; i < e; i++) {
    int key = perm[i];
    int j = i - 1;
    while (j >= s && perm[j] > key) { perm[j + 1] = perm[j]; j--; }
    perm[j + 1] = key;
  }
}

// ---------------- K1: node up-projections ----------------------------------
__global__ __launch_bounds__(256) void k_node_up(
    const float* __restrict__ nf,
    const float* __restrict__ Wsc,
    const float* __restrict__ Wu0,
    const float* __restrict__ Wu1,
    float* __restrict__ ws)  // planes: 0 NS, 1 SU, 2..4 VU_i
{
  __shared__ float sIn[64][132];
  __shared__ float sW[128][128];
  const int n0 = blockIdx.x * 64;
  const int which = blockIdx.y;
  const float* W = (which == 0) ? Wsc : ((which == 1) ? Wu0 : Wu1);
  float* out = ws + (size_t)which * NP;

  for (int idx = threadIdx.x; idx < 128 * 32; idx += 256) {
    int r = idx >> 5, fc = (idx & 31) << 2;
    *(float4*)&sW[r][fc] = *(const float4*)&W[r * 128 + fc];
  }
  if (which < 2) {
    for (int idx = threadIdx.x; idx < 64 * 32; idx += 256) {
      int r = idx >> 5, fc = (idx & 31) << 2;
      int n = n0 + r;
      float4 v = {0.f, 0.f, 0.f, 0.f};
      if (n < N_NODESC) v = *(const float4*)&nf[(size_t)n * 512 + fc];
      *(float4*)&sIn[r][fc] = v;
    }
  } else {
    int comp = which - 2;
    for (int idx = threadIdx.x; idx < 64 * 128; idx += 256) {
      int r = idx >> 7, u = idx & 127;
      int n = n0 + r;
      sIn[r][u] = (n < N_NODESC) ? nf[(size_t)n * 512 + 128 + u * 3 + comp] : 0.f;
    }
  }
  __syncthreads();

  const int r0 = (threadIdx.x >> 4) * 4;
  const int c0 = (threadIdx.x & 15) * 8;
  float acc[4][8] = {};
  #pragma unroll 4
  for (int k = 0; k < 128; k++) {
    float a[4];
    #pragma unroll
    for (int j = 0; j < 4; j++) a[j] = sIn[r0 + j][k];
    float w[8];
    *(float4*)&w[0] = *(const float4*)&sW[k][c0];
    *(float4*)&w[4] = *(const float4*)&sW[k][c0 + 4];
    #pragma unroll
    for (int j = 0; j < 4; j++)
      #pragma unroll
      for (int c = 0; c < 8; c++) acc[j][c] += a[j] * w[c];
  }
  #pragma unroll
  for (int j = 0; j < 4; j++) {
    int n = n0 + r0 + j;
    if (n < N_NODESC) {
      float o[8];
      #pragma unroll
      for (int c = 0; c < 8; c++) o[c] = acc[j][c] * INV128;
      *(float4*)&out[(size_t)n * 128 + c0] = *(float4*)&o[0];
      *(float4*)&out[(size_t)n * 128 + c0 + 4] = *(float4*)&o[4];
    }
  }
}

// ---------------- fused edge kernel: MLP(3 layers) + messages + seg-reduce --
__global__ __launch_bounds__(256) void k_edge_fused(
    const float* __restrict__ NS,
    const float* __restrict__ SU,
    const float* __restrict__ VU,   // 3 planes
    const float* __restrict__ ef,
    const float* __restrict__ len,
    const float* __restrict__ ea,
    const int* __restrict__ eidx,
    const int* __restrict__ perm,
    const int* __restrict__ row_start,
    const float* __restrict__ W1,
    const float* __restrict__ b1,
    const float* __restrict__ W2,
    const float* __restrict__ b2,
    const float* __restrict__ W3,
    float* __restrict__ MSG,        // 8 planes: ms0, ms1, mva0..2, mvb0..2
    float* __restrict__ CONT)       // [NBLK_TOT][1024]
{
  __shared__ float sA[64][132];     // input staging -> h1 -> h2
  __shared__ float sW[64][132];     // weight tiles; message transpose in emit
  __shared__ float sT[10][128];     // W1 tail rows + b1
  __shared__ float sEL[64][12];
  __shared__ float sY4[64][4];
  __shared__ int sSnd[64], sRcv[64];
  __shared__ int sContFirst;

  const int gblk = blockIdx.x;
  const int j0 = gblk * 64;
  if (threadIdx.x < 64) {
    int r = threadIdx.x;
    int e = perm[j0 + r];
    sSnd[r] = eidx[e];
    sRcv[r] = eidx[N_EDGESC + e];
    #pragma unroll
    for (int q = 0; q < 8; q++) sEL[r][q] = ef[(size_t)e * 8 + q];
    sEL[r][8] = len[e];
    *(float4*)&sY4[r][0] = *(const float4*)&ea[(size_t)e * 4];
    if (r == 0) sContFirst = (row_start[eidx[N_EDGESC + e]] != j0) ? 1 : 0;
  }
  for (int idx = threadIdx.x; idx < 10 * 128; idx += 256) {
    int r = idx >> 7, c = idx & 127;
    sT[r][c] = (r < 9) ? W1[(256 + r) * 128 + c] : b1[c];
  }

  const int r0 = (threadIdx.x >> 4) * 4;
  const int c0 = (threadIdx.x & 15) * 8;
  const int cid = threadIdx.x;

  // ---------- layer 1 ----------
  float acc[4][8] = {};
  for (int half = 0; half < 2; half++) {
    __syncthreads();  // meta ready (half 0) / previous GEMM done (half 1)
    for (int idx = threadIdx.x; idx < 64 * 32; idx += 256) {
      int r = idx >> 5, fc = (idx & 31) << 2;
      int n = half ? sRcv[r] : sSnd[r];
      *(float4*)&sA[r][fc] = *(const float4*)&NS[(size_t)n * 128 + fc];
    }
    for (int kc = 0; kc < 2; kc++) {
      __syncthreads();
      for (int idx = threadIdx.x; idx < 64 * 32; idx += 256) {
        int r = idx >> 5, fc = (idx & 31) << 2;
        *(float4*)&sW[r][fc] = *(const float4*)&W1[((half * 2 + kc) * 64 + r) * 128 + fc];
      }
      __syncthreads();
      const int kof = kc * 64;
      #pragma unroll 4
      for (int k = 0; k < 64; k++) {
        float a[4];
        #pragma unroll
        for (int j = 0; j < 4; j++) a[j] = sA[r0 + j][kof + k];
        float w[8];
        *(float4*)&w[0] = *(const float4*)&sW[k][c0];
        *(float4*)&w[4] = *(const float4*)&sW[k][c0 + 4];
        #pragma unroll
        for (int j = 0; j < 4; j++)
          #pragma unroll
          for (int c = 0; c < 8; c++) acc[j][c] += a[j] * w[c];
      }
      __syncthreads();
    }
  }
  // tail + bias + silu -> h1 into sA (GEMM reads done; last sync above)
  #pragma unroll
  for (int j = 0; j < 4; j++) {
    int r = r0 + j;
    #pragma unroll
    for (int c = 0; c < 8; c++) {
      float v = acc[j][c] + sT[9][c0 + c];
      #pragma unroll
      for (int t = 0; t < 9; t++) v += sEL[r][t] * sT[t][c0 + c];
      sA[r][c0 + c] = silu_f(v);
    }
  }
  // ---------- layer 2 ----------
  float acc2[4][8] = {};
  for (int kc = 0; kc < 2; kc++) {
    __syncthreads();
    for (int idx = threadIdx.x; idx < 64 * 32; idx += 256) {
      int r = idx >> 5, fc = (idx & 31) << 2;
      *(float4*)&sW[r][fc] = *(const float4*)&W2[(kc * 64 + r) * 128 + fc];
    }
    __syncthreads();
    const int kof = kc * 64;
    #pragma unroll 4
    for (int k = 0; k < 64; k++) {
      float a[4];
      #pragma unroll
      for (int j = 0; j < 4; j++) a[j] = sA[r0 + j][kof + k];
      float w[8];
      *(float4*)&w[0] = *(const float4*)&sW[k][c0];
      *(float4*)&w[4] = *(const float4*)&sW[k][c0 + 4];
      #pragma unroll
      for (int j = 0; j < 4; j++)
        #pragma unroll
        for (int c = 0; c < 8; c++) acc2[j][c] += a[j] * w[c];
    }
  }
  __syncthreads();  // all h1 reads done before overwrite
  #pragma unroll
  for (int j = 0; j < 4; j++) {
    #pragma unroll
    for (int c = 0; c < 8; c++)
      sA[r0 + j][c0 + c] = silu_f(acc2[j][c] + b2[c0 + c]);
  }
  __syncthreads();  // h2 visible

  // ---------- layer 3 + message emit + segmented reduce ----------
  const bool contF = (sContFirst != 0);
  int snd[4];
  float y0r[4], y1r[4][3];
  #pragma unroll
  for (int j = 0; j < 4; j++) {
    snd[j] = sSnd[r0 + j];
    y0r[j] = sY4[r0 + j][0];
    #pragma unroll
    for (int i = 0; i < 3; i++) y1r[j][i] = sY4[r0 + j][1 + i];
  }
  float seR[4][8];
  #pragma unroll
  for (int j = 0; j < 4; j++)
    #pragma unroll
    for (int c = 0; c < 8; c++)
      seR[j][c] = SU[(size_t)snd[j] * 128 + c0 + c];

  for (int cb = 0; cb < 4; cb++) {
    float acc3[4][8] = {};
    for (int kc = 0; kc < 2; kc++) {
      __syncthreads();
      for (int idx = threadIdx.x; idx < 64 * 32; idx += 256) {
        int r = idx >> 5, fc = (idx & 31) << 2;
        *(float4*)&sW[r][fc] =
            *(const float4*)&W3[(size_t)(kc * 64 + r) * 512 + cb * 128 + fc];
      }
      __syncthreads();
      const int kof = kc * 64;
      #pragma unroll 4
      for (int k = 0; k < 64; k++) {
        float a[4];
        #pragma unroll
        for (int j = 0; j < 4; j++) a[j] = sA[r0 + j][kof + k];
        float w[8];
        *(float4*)&w[0] = *(const float4*)&sW[k][c0];
        *(float4*)&w[4] = *(const float4*)&sW[k][c0 + 4];
        #pragma unroll
        for (int j = 0; j < 4; j++)
          #pragma unroll
          for (int c = 0; c < 8; c++) acc3[j][c] += a[j] * w[c];
      }
    }
    const int npl = (cb == 0 || cb == 3) ? 1 : 3;
    for (int pi = 0; pi < npl; pi++) {
      __syncthreads();  // sW free (GEMM done / previous reduce done)
      #pragma unroll
      for (int j = 0; j < 4; j++) {
        #pragma unroll
        for (int c = 0; c < 8; c++) {
          float m;
          if (cb == 0) {
            m = acc3[j][c] * seR[j][c] * y0r[j];
          } else if (cb == 1) {
            m = acc3[j][c] * seR[j][c] * y1r[j][pi];
          } else if (cb == 2) {
            float ve = VU[(size_t)pi * NP + (size_t)snd[j] * 128 + c0 + c];
            m = acc3[j][c] * y0r[j] * ve;
          } else {
            float dot = VU[(size_t)snd[j] * 128 + c0 + c] * y1r[j][0]
                      + VU[(size_t)NP + (size_t)snd[j] * 128 + c0 + c] * y1r[j][1]
                      + VU[2 * (size_t)NP + (size_t)snd[j] * 128 + c0 + c] * y1r[j][2];
            m = acc3[j][c] * dot * INV_SQRT3C;
          }
          sW[r0 + j][c0 + c] = m;
        }
      }
      const int p = (cb == 0) ? 0 : ((cb == 3) ? 1 : ((cb == 1) ? 2 + pi : 5 + pi));
      __syncthreads();
      if (cid < 128) {
        float sum = 0.f;
        int prev = sRcv[0];
        int segl = 0;
        for (int e2 = 0; e2 < 64; e2++) {
          int rv = sRcv[e2];
          if (rv != prev) {
            if (segl == 0 && contF)
              CONT[(size_t)gblk * 1024 + p * 128 + cid] = sum;
            else
              MSG[(size_t)p * NP + (size_t)prev * 128 + cid] = sum;
            prev = rv; segl = e2; sum = 0.f;
          }
          sum += sW[e2][cid];
        }
        if (segl == 0 && contF)
          CONT[(size_t)gblk * 1024 + p * 128 + cid] = sum;
        else
          MSG[(size_t)p * NP + (size_t)prev * 128 + cid] = sum;
      }
    }
  }
}

// ---------------- fixup: add continuation partials into MSG ----------------
__global__ __launch_bounds__(256) void k_fixup(float* __restrict__ MSG,
                                               const float* __restrict__ CONT,
                                               const int* __restrict__ row_start) {
  int t = blockIdx.x * 256 + threadIdx.x;
  int n = t >> 5;
  int c4 = (t & 31) * 4;
  if (n >= N_NODESC) return;
  int s = row_start[n], e = row_start[n + 1];
  if (e <= s) return;
  int b0 = s >> 6, b1 = (e - 1) >> 6;
  if (b1 <= b0) return;
  for (int p = 0; p < 8; p++) {
    float4 v = *(float4*)&MSG[(size_t)p * NP + (size_t)n * 128 + c4];
    for (int b = b0 + 1; b <= b1; b++) {
      const float4 u = *(const float4*)&CONT[(size_t)b * 1024 + p * 128 + c4];
      v.x += u.x; v.y += u.y; v.z += u.z; v.w += u.w;
    }
    *(float4*)&MSG[(size_t)p * NP + (size_t)n * 128 + c4] = v;
  }
}

// ---------------- K4: output GEMMs ----------------------------------------
__global__ __launch_bounds__(256) void k_out(
    const float* __restrict__ MSG,
    const float* __restrict__ Wo0,
    const float* __restrict__ Wo1,
    float* __restrict__ out)
{
  __shared__ float sA[64][132];
  __shared__ float sB[64][132];
  __shared__ float sW[64][128];
  const int n0 = blockIdx.x * 64;
  const int y = blockIdx.y;
  const float* W = (y == 0) ? Wo0 : Wo1;
  const float* pA = MSG + (size_t)((y == 0) ? 0 : (1 + y)) * NP;
  const float* pB = MSG + (size_t)((y == 0) ? 1 : (4 + y)) * NP;

  for (int idx = threadIdx.x; idx < 64 * 32; idx += 256) {
    int r = idx >> 5, fc = (idx & 31) << 2;
    int n = n0 + r;
    float4 va = {0.f, 0.f, 0.f, 0.f}, vb = {0.f, 0.f, 0.f, 0.f};
    if (n < N_NODESC) {
      va = *(const float4*)&pA[(size_t)n * 128 + fc];
      vb = *(const float4*)&pB[(size_t)n * 128 + fc];
    }
    *(float4*)&sA[r][fc] = va;
    *(float4*)&sB[r][fc] = vb;
  }
  const int r0 = (threadIdx.x >> 4) * 4;
  const int c0 = (threadIdx.x & 15) * 8;
  float acc[4][8] = {};
  for (int kc = 0; kc < 4; kc++) {
    __syncthreads();
    for (int idx = threadIdx.x; idx < 64 * 32; idx += 256) {
      int r = idx >> 5, fc = (idx & 31) << 2;
      *(float4*)&sW[r][fc] = *(const float4*)&W[(kc * 64 + r) * 128 + fc];
    }
    __syncthreads();
    const float (*sIn)[132] = (kc < 2) ? sA : sB;
    const int kof = (kc & 1) * 64;
    #pragma unroll 4
    for (int k = 0; k < 64; k++) {
      float a[4];
      #pragma unroll
      for (int j = 0; j < 4; j++) a[j] = sIn[r0 + j][kof + k];
      float w[8];
      *(float4*)&w[0] = *(const float4*)&sW[k][c0];
      *(float4*)&w[4] = *(const float4*)&sW[k][c0 + 4];
      #pragma unroll
      for (int j = 0; j < 4; j++)
        #pragma unroll
        for (int c = 0; c < 8; c++) acc[j][c] += a[j] * w[c];
    }
  }
  #pragma unroll
  for (int j = 0; j < 4; j++) {
    int n = n0 + r0 + j;
    if (n < N_NODESC) {
      #pragma unroll
      for (int c = 0; c < 8; c++)
        out[(size_t)n * 512 + (size_t)(c0 + c) * 4 + y] = acc[j][c] * SCALE_OUT;
    }
  }
}

extern "C" void kernel_launch(void* const* d_in, const int* in_sizes, int n_in,
                              void* d_out, int out_size, void* d_ws, size_t ws_size,
                              hipStream_t stream) {
  const float* nf  = (const float*)d_in[0];
  const float* ea  = (const float*)d_in[1];
  const float* ef  = (const float*)d_in[2];
  const float* len = (const float*)d_in[3];
  const int*   ei  = (const int*)d_in[4];
  const float* Wsc = (const float*)d_in[5];
  const float* Wu0 = (const float*)d_in[6];
  const float* Wu1 = (const float*)d_in[7];
  const float* W1  = (const float*)d_in[8];
  const float* b1  = (const float*)d_in[9];
  const float* W2  = (const float*)d_in[10];
  const float* b2  = (const float*)d_in[11];
  const float* W3  = (const float*)d_in[12];
  const float* Wo0 = (const float*)d_in[13];
  const float* Wo1 = (const float*)d_in[14];
  float* out = (float*)d_out;
  float* ws  = (float*)d_ws;

  const size_t NPs = (size_t)NP;
  float* NS   = ws;                            // 1 plane
  float* SU   = ws + NPs;                      // 1 plane
  float* VU   = ws + 2 * NPs;                  // 3 planes
  float* MSG  = ws + 5 * NPs;                  // 8 planes
  float* CONT = ws + 13 * NPs;                 // NBLK_TOT*1024
  int* perm      = (int*)(CONT + (size_t)NBLK_TOT * 1024);
  int* deg       = perm + N_EDGESC;
  int* cursor    = deg + N_NODESC;
  int* row_start = cursor + N_NODESC;          // N_NODESC+1 ints

  hipMemsetAsync(deg, 0, N_NODESC * sizeof(int), stream);
  hipMemsetAsync(cursor, 0, N_NODESC * sizeof(int), stream);
  hipMemsetAsync(MSG, 0, 8 * NPs * sizeof(float), stream);

  k_hist<<<(N_EDGESC + 255) / 256, 256, 0, stream>>>(ei, deg);
  k_scan<<<1, 1024, 0, stream>>>(deg, row_start);
  k_scatter<<<(N_EDGESC + 255) / 256, 256, 0, stream>>>(ei, row_start, cursor, perm);
  k_sortseg<<<(N_NODESC + 255) / 256, 256, 0, stream>>>(perm, row_start);

  k_node_up<<<dim3(157, 5), 256, 0, stream>>>(nf, Wsc, Wu0, Wu1, ws);

  k_edge_fused<<<NBLK_TOT, 256, 0, stream>>>(NS, SU, VU, ef, len, ea, ei, perm,
                                             row_start, W1, b1, W2, b2, W3,
                                             MSG, CONT);

  k_fixup<<<(N_NODESC * 32 + 255) / 256, 256, 0, stream>>>(MSG, CONT, row_start);
  k_out<<<dim3(157, 4), 256, 0, stream>>>(MSG, Wo0, Wo1, out);
}

// Round 4
// 749.947 us; speedup vs baseline: 6.8785x; 1.5704x over previous
//
#include <hip/hip_runtime.h>

#define N_NODESC 10000
#define N_EDGESC 160000
#define NBLK_TOT 2500                 // N_EDGESC/64
#define NP       (N_NODESC*128)       // plane size (floats)
#define INV128   0.08838834764831845f // 1/sqrt(128)
#define INV_SQRT3C 0.5773502691896258f
#define SCALE_OUT 0.00390625f         // (1/sqrt(256))/16

typedef __attribute__((ext_vector_type(8))) short bf16x8;
typedef __attribute__((ext_vector_type(4))) float f32x4;

__device__ __forceinline__ float silu_f(float x) {
  return x / (1.f + __expf(-x));
}
__device__ __forceinline__ ushort f2bf_rne(float x) {
  uint u = __float_as_uint(x);
  uint r = (u + 0x7FFFu + ((u >> 16) & 1u)) >> 16;
  return (ushort)r;
}
__device__ __forceinline__ float bf2f(ushort h) {
  return __uint_as_float(((uint)h) << 16);
}

// ---------------- CSR build ------------------------------------------------
__global__ __launch_bounds__(256) void k_hist(const int* __restrict__ eidx,
                                              int* __restrict__ deg) {
  int e = blockIdx.x * 256 + threadIdx.x;
  if (e < N_EDGESC) atomicAdd(&deg[eidx[N_EDGESC + e]], 1);
}

__global__ __launch_bounds__(1024) void k_scan(const int* __restrict__ deg,
                                               int* __restrict__ row_start) {
  __shared__ int buf[1024];
  __shared__ int sc;
  if (threadIdx.x == 0) sc = 0;
  __syncthreads();
  for (int base = 0; base < N_NODESC; base += 1024) {
    int i = base + threadIdx.x;
    int d = (i < N_NODESC) ? deg[i] : 0;
    int v = d;
    buf[threadIdx.x] = v;
    __syncthreads();
    for (int off = 1; off < 1024; off <<= 1) {
      int t = (threadIdx.x >= off) ? buf[threadIdx.x - off] : 0;
      __syncthreads();
      v += t;
      buf[threadIdx.x] = v;
      __syncthreads();
    }
    if (i < N_NODESC) row_start[i] = sc + v - d;
    int tot = buf[1023];
    __syncthreads();
    if (threadIdx.x == 0) sc += tot;
    __syncthreads();
  }
  if (threadIdx.x == 0) row_start[N_NODESC] = sc;
}

__global__ __launch_bounds__(256) void k_scatter(const int* __restrict__ eidx,
                                                 const int* __restrict__ row_start,
                                                 int* __restrict__ cursor,
                                                 int* __restrict__ perm) {
  int e = blockIdx.x * 256 + threadIdx.x;
  if (e < N_EDGESC) {
    int r = eidx[N_EDGESC + e];
    int pos = row_start[r] + atomicAdd(&cursor[r], 1);
    perm[pos] = e;
  }
}

__global__ __launch_bounds__(256) void k_sortseg(int* __restrict__ perm,
                                                 const int* __restrict__ row_start) {
  int n = blockIdx.x * 256 + threadIdx.x;
  if (n >= N_NODESC) return;
  int s = row_start[n], e = row_start[n + 1];
  for (int i = s + 1; i < e; i++) {
    int key = perm[i];
    int j = i - 1;
    while (j >= s && perm[j] > key) { perm[j + 1] = perm[j]; j--; }
    perm[j + 1] = key;
  }
}

// ---------------- weight prep: transposed hi/lo bf16 -----------------------
__global__ __launch_bounds__(256) void k_wprep(
    const float* __restrict__ W1, const float* __restrict__ W2,
    const float* __restrict__ W3,
    ushort* __restrict__ W1tH, ushort* __restrict__ W1tL,
    ushort* __restrict__ W2tH, ushort* __restrict__ W2tL,
    ushort* __restrict__ W3tH, ushort* __restrict__ W3tL) {
  int id = blockIdx.x * 256 + threadIdx.x;
  float v;
  ushort *dh, *dl;
  int di;
  if (id < 32768) {           // W1t [128][256] from W1[k][n], k<256
    int n = id >> 8, k = id & 255;
    v = W1[k * 128 + n]; dh = W1tH; dl = W1tL; di = id;
  } else if (id < 49152) {    // W2t [128][128]
    int t = id - 32768;
    int n = t >> 7, k = t & 127;
    v = W2[k * 128 + n]; dh = W2tH; dl = W2tL; di = t;
  } else if (id < 114688) {   // W3t [512][128] from W3[k][n], n<512
    int t = id - 49152;
    int n = t >> 7, k = t & 127;
    v = W3[k * 512 + n]; dh = W3tH; dl = W3tL; di = t;
  } else return;
  ushort hi = f2bf_rne(v);
  dh[di] = hi;
  dl[di] = f2bf_rne(v - bf2f(hi));
}

// ---------------- K1: node up-projections ----------------------------------
__global__ __launch_bounds__(256) void k_node_up(
    const float* __restrict__ nf,
    const float* __restrict__ Wsc,
    const float* __restrict__ Wu0,
    const float* __restrict__ Wu1,
    ushort* __restrict__ NShi,
    ushort* __restrict__ NSlo,
    float* __restrict__ SU,
    float* __restrict__ VU)
{
  __shared__ float sIn[64][132];
  __shared__ float sW[128][128];
  const int n0 = blockIdx.x * 64;
  const int which = blockIdx.y;  // 0 NS(->bf16 hi/lo), 1 SU, 2..4 VU comp
  const float* W = (which == 0) ? Wsc : ((which == 1) ? Wu0 : Wu1);

  for (int idx = threadIdx.x; idx < 128 * 32; idx += 256) {
    int r = idx >> 5, fc = (idx & 31) << 2;
    *(float4*)&sW[r][fc] = *(const float4*)&W[r * 128 + fc];
  }
  if (which < 2) {
    for (int idx = threadIdx.x; idx < 64 * 32; idx += 256) {
      int r = idx >> 5, fc = (idx & 31) << 2;
      int n = n0 + r;
      float4 v = {0.f, 0.f, 0.f, 0.f};
      if (n < N_NODESC) v = *(const float4*)&nf[(size_t)n * 512 + fc];
      *(float4*)&sIn[r][fc] = v;
    }
  } else {
    int comp = which - 2;
    for (int idx = threadIdx.x; idx < 64 * 128; idx += 256) {
      int r = idx >> 7, u = idx & 127;
      int n = n0 + r;
      sIn[r][u] = (n < N_NODESC) ? nf[(size_t)n * 512 + 128 + u * 3 + comp] : 0.f;
    }
  }
  __syncthreads();

  const int r0 = (threadIdx.x >> 4) * 4;
  const int c0 = (threadIdx.x & 15) * 8;
  float acc[4][8] = {};
  #pragma unroll 4
  for (int k = 0; k < 128; k++) {
    float a[4];
    #pragma unroll
    for (int j = 0; j < 4; j++) a[j] = sIn[r0 + j][k];
    float w[8];
    *(float4*)&w[0] = *(const float4*)&sW[k][c0];
    *(float4*)&w[4] = *(const float4*)&sW[k][c0 + 4];
    #pragma unroll
    for (int j = 0; j < 4; j++)
      #pragma unroll
      for (int c = 0; c < 8; c++) acc[j][c] += a[j] * w[c];
  }
  #pragma unroll
  for (int j = 0; j < 4; j++) {
    int n = n0 + r0 + j;
    if (n < N_NODESC) {
      if (which == 0) {
        #pragma unroll
        for (int c = 0; c < 8; c++) {
          float o = acc[j][c] * INV128;
          ushort hi = f2bf_rne(o);
          NShi[(size_t)n * 128 + c0 + c] = hi;
          NSlo[(size_t)n * 128 + c0 + c] = f2bf_rne(o - bf2f(hi));
        }
      } else {
        float* out = (which == 1) ? SU : (VU + (size_t)(which - 2) * NP);
        float o[8];
        #pragma unroll
        for (int c = 0; c < 8; c++) o[c] = acc[j][c] * INV128;
        *(float4*)&out[(size_t)n * 128 + c0] = *(float4*)&o[0];
        *(float4*)&out[(size_t)n * 128 + c0 + 4] = *(float4*)&o[4];
      }
    }
  }
}

// ---------------- fused edge kernel (MFMA split-bf16) ----------------------
#define GEMM_PASS2(ACC)                                                        \
  _Pragma("unroll") for (int s = 0; s < 4; s++) {                              \
    bf16x8 ah = *(const bf16x8*)&sAh[ar][s * 32 + lq * 8];                     \
    bf16x8 al = *(const bf16x8*)&sAl[ar][s * 32 + lq * 8];                     \
    _Pragma("unroll") for (int nt = 0; nt < 8; nt++) {                         \
      bf16x8 bb = *(const bf16x8*)&sB[nt * 16 + ln][s * 32 + lq * 8];          \
      ACC[nt] = __builtin_amdgcn_mfma_f32_16x16x32_bf16(ah, bb, ACC[nt], 0, 0, 0); \
      ACC[nt] = __builtin_amdgcn_mfma_f32_16x16x32_bf16(al, bb, ACC[nt], 0, 0, 0); \
    }                                                                          \
  }

#define GEMM_PASS1(ACC)                                                        \
  _Pragma("unroll") for (int s = 0; s < 4; s++) {                              \
    bf16x8 ah = *(const bf16x8*)&sAh[ar][s * 32 + lq * 8];                     \
    _Pragma("unroll") for (int nt = 0; nt < 8; nt++) {                         \
      bf16x8 bb = *(const bf16x8*)&sB[nt * 16 + ln][s * 32 + lq * 8];          \
      ACC[nt] = __builtin_amdgcn_mfma_f32_16x16x32_bf16(ah, bb, ACC[nt], 0, 0, 0); \
    }                                                                          \
  }

#define REDUCE(P, MI)                                                          \
  __syncthreads();                                                             \
  if (cid < 128) {                                                             \
    float sum = 0.f; int prev = sRcv[0]; int segl = 0;                         \
    for (int e2 = 0; e2 < 64; e2++) {                                          \
      int rv = sRcv[e2];                                                       \
      if (rv != prev) {                                                        \
        if (segl == 0 && contF) CONT[(size_t)gblk * 1024 + (P) * 128 + cid] = sum; \
        else MSG[(size_t)(P) * NP + (size_t)prev * 128 + cid] = sum;           \
        prev = rv; segl = e2; sum = 0.f;                                       \
      }                                                                        \
      float mv = sMsg[e2][cid];                                                \
      sum += ((MI) >= 0 ? mv * sY4[e2][MI] : mv);                              \
    }                                                                          \
    if (segl == 0 && contF) CONT[(size_t)gblk * 1024 + (P) * 128 + cid] = sum; \
    else MSG[(size_t)(P) * NP + (size_t)prev * 128 + cid] = sum;               \
  }                                                                            \
  __syncthreads();

__global__ __launch_bounds__(256, 2) void k_edge_fused(
    const ushort* __restrict__ NShi,
    const ushort* __restrict__ NSlo,
    const float* __restrict__ SU,
    const float* __restrict__ VU,   // 3 planes
    const float* __restrict__ ef,
    const float* __restrict__ len,
    const float* __restrict__ ea,
    const int* __restrict__ eidx,
    const int* __restrict__ perm,
    const int* __restrict__ row_start,
    const float* __restrict__ W1,   // f32, for tail rows
    const float* __restrict__ b1,
    const float* __restrict__ b2,
    const ushort* __restrict__ W1tH, const ushort* __restrict__ W1tL,
    const ushort* __restrict__ W2tH, const ushort* __restrict__ W2tL,
    const ushort* __restrict__ W3tH, const ushort* __restrict__ W3tL,
    float* __restrict__ MSG,        // 8 planes
    float* __restrict__ CONT)       // [NBLK_TOT][1024]
{
  __shared__ ushort sAh[64][136];
  __shared__ ushort sAl[64][136];
  __shared__ ushort sB[128][136];   // W tile during GEMM; f32 msg buffer in emit
  __shared__ float sT[11][128];     // W1 tail rows (9), b1, b2
  __shared__ float sEL[64][12];
  __shared__ float sY4[64][4];
  __shared__ int sSnd[64], sRcv[64];
  __shared__ int sContFirst;
  float (*sMsg)[132] = (float (*)[132])&sB[0][0];   // 64*132*4 = 33792 <= 34816

  const int gblk = blockIdx.x;
  const int j0 = gblk * 64;
  const int cid = threadIdx.x;
  const int wid = threadIdx.x >> 6;
  const int lane = threadIdx.x & 63;
  const int lq = lane >> 4;    // 0..3
  const int ln = lane & 15;
  const int ar = wid * 16 + ln;  // A-fragment row (edge)

  if (threadIdx.x < 64) {
    int r = threadIdx.x;
    int e = perm[j0 + r];
    sSnd[r] = eidx[e];
    sRcv[r] = eidx[N_EDGESC + e];
    #pragma unroll
    for (int q = 0; q < 8; q++) sEL[r][q] = ef[(size_t)e * 8 + q];
    sEL[r][8] = len[e];
    *(float4*)&sY4[r][0] = *(const float4*)&ea[(size_t)e * 4];
    if (r == 0) sContFirst = (row_start[eidx[N_EDGESC + e]] != j0) ? 1 : 0;
  }
  for (int idx = threadIdx.x; idx < 11 * 128; idx += 256) {
    int r = idx >> 7, c2 = idx & 127;
    sT[r][c2] = (r < 9) ? W1[(256 + r) * 128 + c2] : (r == 9 ? b1[c2] : b2[c2]);
  }
  __syncthreads();
  const bool contF = (sContFirst != 0);

  // ---------- layer 1 (K=256 as two 128-halves, 3-term split) ----------
  f32x4 acc[8];
  #pragma unroll
  for (int nt = 0; nt < 8; nt++) acc[nt] = (f32x4){0.f, 0.f, 0.f, 0.f};

  for (int half = 0; half < 2; half++) {
    for (int c = threadIdx.x; c < 64 * 16; c += 256) {
      int r = c >> 4, o = c & 15;
      int n = half ? sRcv[r] : sSnd[r];
      *(uint4*)&sAh[r][o * 8] = *(const uint4*)&NShi[(size_t)n * 128 + o * 8];
      *(uint4*)&sAl[r][o * 8] = *(const uint4*)&NSlo[(size_t)n * 128 + o * 8];
    }
    for (int c = threadIdx.x; c < 128 * 16; c += 256) {
      int n = c >> 4, o = c & 15;
      *(uint4*)&sB[n][o * 8] = *(const uint4*)&W1tH[(size_t)n * 256 + half * 128 + o * 8];
    }
    __syncthreads();
    GEMM_PASS2(acc)
    __syncthreads();
    for (int c = threadIdx.x; c < 128 * 16; c += 256) {
      int n = c >> 4, o = c & 15;
      *(uint4*)&sB[n][o * 8] = *(const uint4*)&W1tL[(size_t)n * 256 + half * 128 + o * 8];
    }
    __syncthreads();
    GEMM_PASS1(acc)
    __syncthreads();
  }
  // tail + bias + silu -> h1 (bf16 hi/lo into sAh/sAl)
  #pragma unroll
  for (int q = 0; q < 4; q++) {
    int rr = wid * 16 + lq * 4 + q;
    float el[9];
    #pragma unroll
    for (int t = 0; t < 9; t++) el[t] = sEL[rr][t];
    #pragma unroll
    for (int nt = 0; nt < 8; nt++) {
      int col = nt * 16 + ln;
      float v = acc[nt][q] + sT[9][col];
      #pragma unroll
      for (int t = 0; t < 9; t++) v += el[t] * sT[t][col];
      float h = silu_f(v);
      ushort hi = f2bf_rne(h);
      sAh[rr][col] = hi;
      sAl[rr][col] = f2bf_rne(h - bf2f(hi));
    }
  }
  __syncthreads();

  // ---------- layer 2 ----------
  f32x4 acc2[8];
  #pragma unroll
  for (int nt = 0; nt < 8; nt++) acc2[nt] = (f32x4){0.f, 0.f, 0.f, 0.f};
  for (int c = threadIdx.x; c < 128 * 16; c += 256) {
    int n = c >> 4, o = c & 15;
    *(uint4*)&sB[n][o * 8] = *(const uint4*)&W2tH[(size_t)n * 128 + o * 8];
  }
  __syncthreads();
  GEMM_PASS2(acc2)
  __syncthreads();
  for (int c = threadIdx.x; c < 128 * 16; c += 256) {
    int n = c >> 4, o = c & 15;
    *(uint4*)&sB[n][o * 8] = *(const uint4*)&W2tL[(size_t)n * 128 + o * 8];
  }
  __syncthreads();
  GEMM_PASS1(acc2)
  __syncthreads();
  #pragma unroll
  for (int q = 0; q < 4; q++) {
    int rr = wid * 16 + lq * 4 + q;
    #pragma unroll
    for (int nt = 0; nt < 8; nt++) {
      int col = nt * 16 + ln;
      float h = silu_f(acc2[nt][q] + sT[10][col]);
      ushort hi = f2bf_rne(h);
      sAh[rr][col] = hi;
      sAl[rr][col] = f2bf_rne(h - bf2f(hi));
    }
  }
  __syncthreads();

  // ---------- layer 3 chunks + emit + segmented reduce ----------
  int erow[4], esnd[4];
  float y0r[4], y1r3[4][3];
  #pragma unroll
  for (int q = 0; q < 4; q++) {
    int rr = wid * 16 + lq * 4 + q;
    erow[q] = rr;
    esnd[q] = sSnd[rr];
    y0r[q] = sY4[rr][0];
    #pragma unroll
    for (int i = 0; i < 3; i++) y1r3[q][i] = sY4[rr][1 + i];
  }
  float se[4][8];
  float dacc[4][8];

  for (int cb = 0; cb < 4; cb++) {
    f32x4 acc3[8];
    #pragma unroll
    for (int nt = 0; nt < 8; nt++) acc3[nt] = (f32x4){0.f, 0.f, 0.f, 0.f};
    for (int c = threadIdx.x; c < 128 * 16; c += 256) {
      int n = c >> 4, o = c & 15;
      *(uint4*)&sB[n][o * 8] = *(const uint4*)&W3tH[(size_t)(cb * 128 + n) * 128 + o * 8];
    }
    __syncthreads();
    GEMM_PASS2(acc3)
    __syncthreads();
    for (int c = threadIdx.x; c < 128 * 16; c += 256) {
      int n = c >> 4, o = c & 15;
      *(uint4*)&sB[n][o * 8] = *(const uint4*)&W3tL[(size_t)(cb * 128 + n) * 128 + o * 8];
    }
    __syncthreads();
    GEMM_PASS1(acc3)
    __syncthreads();   // GEMM done; sB free -> sMsg

    if (cb == 0) {
      #pragma unroll
      for (int q = 0; q < 4; q++)
        #pragma unroll
        for (int nt = 0; nt < 8; nt++)
          se[q][nt] = SU[(size_t)esnd[q] * 128 + nt * 16 + ln];
      #pragma unroll
      for (int q = 0; q < 4; q++)
        #pragma unroll
        for (int nt = 0; nt < 8; nt++)
          sMsg[erow[q]][nt * 16 + ln] = acc3[nt][q] * se[q][nt] * y0r[q];
      REDUCE(0, -1)
    } else if (cb == 1) {
      #pragma unroll
      for (int q = 0; q < 4; q++)
        #pragma unroll
        for (int nt = 0; nt < 8; nt++)
          sMsg[erow[q]][nt * 16 + ln] = acc3[nt][q] * se[q][nt];
      REDUCE(2, 1)
      REDUCE(3, 2)
      REDUCE(4, 3)
    } else if (cb == 2) {
      for (int pi = 0; pi < 3; pi++) {
        float vu[4][8];
        #pragma unroll
        for (int q = 0; q < 4; q++)
          #pragma unroll
          for (int nt = 0; nt < 8; nt++) {
            vu[q][nt] = VU[(size_t)pi * NP + (size_t)esnd[q] * 128 + nt * 16 + ln];
            if (pi == 0) dacc[q][nt] = vu[q][nt] * y1r3[q][0];
            else dacc[q][nt] += vu[q][nt] * y1r3[q][pi];
          }
        #pragma unroll
        for (int q = 0; q < 4; q++)
          #pragma unroll
          for (int nt = 0; nt < 8; nt++)
            sMsg[erow[q]][nt * 16 + ln] = acc3[nt][q] * vu[q][nt];
        if (pi == 0) { REDUCE(5, 0) }
        else if (pi == 1) { REDUCE(6, 0) }
        else { REDUCE(7, 0) }
      }
    } else {
      #pragma unroll
      for (int q = 0; q < 4; q++)
        #pragma unroll
        for (int nt = 0; nt < 8; nt++)
          sMsg[erow[q]][nt * 16 + ln] = acc3[nt][q] * dacc[q][nt] * INV_SQRT3C;
      REDUCE(1, -1)
    }
  }
}

// ---------------- fixup: add continuation partials into MSG ----------------
__global__ __launch_bounds__(256) void k_fixup(float* __restrict__ MSG,
                                               const float* __restrict__ CONT,
                                               const int* __restrict__ row_start) {
  int t = blockIdx.x * 256 + threadIdx.x;
  int n = t >> 5;
  int c4 = (t & 31) * 4;
  if (n >= N_NODESC) return;
  int s = row_start[n], e = row_start[n + 1];
  if (e <= s) return;
  int b0 = s >> 6, b1 = (e - 1) >> 6;
  if (b1 <= b0) return;
  for (int p = 0; p < 8; p++) {
    float4 v = *(float4*)&MSG[(size_t)p * NP + (size_t)n * 128 + c4];
    for (int b = b0 + 1; b <= b1; b++) {
      const float4 u = *(const float4*)&CONT[(size_t)b * 1024 + p * 128 + c4];
      v.x += u.x; v.y += u.y; v.z += u.z; v.w += u.w;
    }
    *(float4*)&MSG[(size_t)p * NP + (size_t)n * 128 + c4] = v;
  }
}

// ---------------- K4: output GEMMs ----------------------------------------
__global__ __launch_bounds__(256) void k_out(
    const float* __restrict__ MSG,
    const float* __restrict__ Wo0,
    const float* __restrict__ Wo1,
    float* __restrict__ out)
{
  __shared__ float sA[64][132];
  __shared__ float sB2[64][132];
  __shared__ float sW[64][128];
  const int n0 = blockIdx.x * 64;
  const int y = blockIdx.y;
  const float* W = (y == 0) ? Wo0 : Wo1;
  const float* pA = MSG + (size_t)((y == 0) ? 0 : (1 + y)) * NP;
  const float* pB = MSG + (size_t)((y == 0) ? 1 : (4 + y)) * NP;

  for (int idx = threadIdx.x; idx < 64 * 32; idx += 256) {
    int r = idx >> 5, fc = (idx & 31) << 2;
    int n = n0 + r;
    float4 va = {0.f, 0.f, 0.f, 0.f}, vb = {0.f, 0.f, 0.f, 0.f};
    if (n < N_NODESC) {
      va = *(const float4*)&pA[(size_t)n * 128 + fc];
      vb = *(const float4*)&pB[(size_t)n * 128 + fc];
    }
    *(float4*)&sA[r][fc] = va;
    *(float4*)&sB2[r][fc] = vb;
  }
  const int r0 = (threadIdx.x >> 4) * 4;
  const int c0 = (threadIdx.x & 15) * 8;
  float acc[4][8] = {};
  for (int kc = 0; kc < 4; kc++) {
    __syncthreads();
    for (int idx = threadIdx.x; idx < 64 * 32; idx += 256) {
      int r = idx >> 5, fc = (idx & 31) << 2;
      *(float4*)&sW[r][fc] = *(const float4*)&W[(kc * 64 + r) * 128 + fc];
    }
    __syncthreads();
    const float (*sIn)[132] = (kc < 2) ? sA : sB2;
    const int kof = (kc & 1) * 64;
    #pragma unroll 4
    for (int k = 0; k < 64; k++) {
      float a[4];
      #pragma unroll
      for (int j = 0; j < 4; j++) a[j] = sIn[r0 + j][kof + k];
      float w[8];
      *(float4*)&w[0] = *(const float4*)&sW[k][c0];
      *(float4*)&w[4] = *(const float4*)&sW[k][c0 + 4];
      #pragma unroll
      for (int j = 0; j < 4; j++)
        #pragma unroll
        for (int c = 0; c < 8; c++) acc[j][c] += a[j] * w[c];
    }
  }
  #pragma unroll
  for (int j = 0; j < 4; j++) {
    int n = n0 + r0 + j;
    if (n < N_NODESC) {
      #pragma unroll
      for (int c = 0; c < 8; c++)
        out[(size_t)n * 512 + (size_t)(c0 + c) * 4 + y] = acc[j][c] * SCALE_OUT;
    }
  }
}

extern "C" void kernel_launch(void* const* d_in, const int* in_sizes, int n_in,
                              void* d_out, int out_size, void* d_ws, size_t ws_size,
                              hipStream_t stream) {
  const float* nf  = (const float*)d_in[0];
  const float* ea  = (const float*)d_in[1];
  const float* ef  = (const float*)d_in[2];
  const float* len = (const float*)d_in[3];
  const int*   ei  = (const int*)d_in[4];
  const float* Wsc = (const float*)d_in[5];
  const float* Wu0 = (const float*)d_in[6];
  const float* Wu1 = (const float*)d_in[7];
  const float* W1  = (const float*)d_in[8];
  const float* b1  = (const float*)d_in[9];
  const float* W2  = (const float*)d_in[10];
  const float* b2  = (const float*)d_in[11];
  const float* W3  = (const float*)d_in[12];
  const float* Wo0 = (const float*)d_in[13];
  const float* Wo1 = (const float*)d_in[14];
  float* out = (float*)d_out;
  float* ws  = (float*)d_ws;

  const size_t NPs = (size_t)NP;
  float* SU   = ws;                            // 1 plane
  float* VU   = ws + NPs;                      // 3 planes
  float* MSG  = ws + 4 * NPs;                  // 8 planes
  float* CONT = ws + 12 * NPs;                 // NBLK_TOT*1024
  ushort* NShi = (ushort*)(CONT + (size_t)NBLK_TOT * 1024);
  ushort* NSlo = NShi + NPs;
  ushort* W1tH = NSlo + NPs;
  ushort* W1tL = W1tH + 32768;
  ushort* W2tH = W1tL + 32768;
  ushort* W2tL = W2tH + 16384;
  ushort* W3tH = W2tL + 16384;
  ushort* W3tL = W3tH + 65536;
  int* perm      = (int*)(W3tL + 65536);
  int* deg       = perm + N_EDGESC;
  int* cursor    = deg + N_NODESC;
  int* row_start = cursor + N_NODESC;          // N_NODESC+1 ints

  hipMemsetAsync(deg, 0, N_NODESC * sizeof(int), stream);
  hipMemsetAsync(cursor, 0, N_NODESC * sizeof(int), stream);
  hipMemsetAsync(MSG, 0, 8 * NPs * sizeof(float), stream);

  k_hist<<<(N_EDGESC + 255) / 256, 256, 0, stream>>>(ei, deg);
  k_scan<<<1, 1024, 0, stream>>>(deg, row_start);
  k_scatter<<<(N_EDGESC + 255) / 256, 256, 0, stream>>>(ei, row_start, cursor, perm);
  k_sortseg<<<(N_NODESC + 255) / 256, 256, 0, stream>>>(perm, row_start);
  k_wprep<<<448, 256, 0, stream>>>(W1, W2, W3, W1tH, W1tL, W2tH, W2tL, W3tH, W3tL);

  k_node_up<<<dim3(157, 5), 256, 0, stream>>>(nf, Wsc, Wu0, Wu1, NShi, NSlo, SU, VU);

  k_edge_fused<<<NBLK_TOT, 256, 0, stream>>>(NShi, NSlo, SU, VU, ef, len, ea, ei,
                                             perm, row_start, W1, b1, b2,
                                             W1tH, W1tL, W2tH, W2tL, W3tH, W3tL,
                                             MSG, CONT);

  k_fixup<<<(N_NODESC * 32 + 255) / 256, 256, 0, stream>>>(MSG, CONT, row_start);
  k_out<<<dim3(157, 4), 256, 0, stream>>>(MSG, Wo0, Wo1, out);
}

// Round 5
// 731.036 us; speedup vs baseline: 7.0564x; 1.0259x over previous
//
#include <hip/hip_runtime.h>

#define N_NODESC 10000
#define N_EDGESC 160000
#define NBLK_TOT 2500                 // N_EDGESC/64
#define NP       (N_NODESC*128)       // plane size (floats)
#define INV128   0.08838834764831845f // 1/sqrt(128)
#define INV_SQRT3C 0.5773502691896258f
#define SCALE_OUT 0.00390625f         // (1/sqrt(256))/16

typedef __attribute__((ext_vector_type(8))) short bf16x8;
typedef __attribute__((ext_vector_type(4))) float f32x4;

__device__ __forceinline__ float silu_f(float x) {
  return x / (1.f + __expf(-x));
}
__device__ __forceinline__ ushort f2bf_rne(float x) {
  uint u = __float_as_uint(x);
  uint r = (u + 0x7FFFu + ((u >> 16) & 1u)) >> 16;
  return (ushort)r;
}
__device__ __forceinline__ float bf2f(ushort h) {
  return __uint_as_float(((uint)h) << 16);
}

// ---------------- CSR build ------------------------------------------------
__global__ __launch_bounds__(256) void k_hist(const int* __restrict__ eidx,
                                              int* __restrict__ deg) {
  int e = blockIdx.x * 256 + threadIdx.x;
  if (e < N_EDGESC) atomicAdd(&deg[eidx[N_EDGESC + e]], 1);
}

__global__ __launch_bounds__(1024) void k_scan(const int* __restrict__ deg,
                                               int* __restrict__ row_start) {
  __shared__ int buf[1024];
  const int t = threadIdx.x;
  int d[10];
  int loc = 0;
  #pragma unroll
  for (int i = 0; i < 10; i++) {
    int n = t * 10 + i;
    d[i] = (n < N_NODESC) ? deg[n] : 0;
    loc += d[i];
  }
  buf[t] = loc;
  __syncthreads();
  int v = loc;
  for (int off = 1; off < 1024; off <<= 1) {
    int u = (t >= off) ? buf[t - off] : 0;
    __syncthreads();
    v += u;
    buf[t] = v;
    __syncthreads();
  }
  int run = v - loc;
  #pragma unroll
  for (int i = 0; i < 10; i++) {
    int n = t * 10 + i;
    if (n < N_NODESC) row_start[n] = run;
    run += d[i];
  }
  if (t == 1023) row_start[N_NODESC] = v;
}

__global__ __launch_bounds__(256) void k_scatter(const int* __restrict__ eidx,
                                                 const int* __restrict__ row_start,
                                                 int* __restrict__ cursor,
                                                 int* __restrict__ perm) {
  int e = blockIdx.x * 256 + threadIdx.x;
  if (e < N_EDGESC) {
    int r = eidx[N_EDGESC + e];
    int pos = row_start[r] + atomicAdd(&cursor[r], 1);
    perm[pos] = e;
  }
}

__global__ __launch_bounds__(256) void k_sortseg(int* __restrict__ perm,
                                                 const int* __restrict__ row_start) {
  int n = blockIdx.x * 256 + threadIdx.x;
  if (n >= N_NODESC) return;
  int s = row_start[n], e = row_start[n + 1];
  for (int i = s + 1; i < e; i++) {
    int key = perm[i];
    int j = i - 1;
    while (j >= s && perm[j] > key) { perm[j + 1] = perm[j]; j--; }
    perm[j + 1] = key;
  }
}

// ---------------- weight prep: tile-linear staging buffer ------------------
// TT tiles (each [128 n][128 k] bf16, 32KB), in stage order:
// t0 W1.k0-127.hi  t1 W1.k0-127.lo  t2 W1.k128-255.hi  t3 W1.k128-255.lo
// t4 W2.hi  t5 W2.lo  t6..t9 W3.cb0..cb3.hi (2-term: no W3 lo)
__global__ __launch_bounds__(256) void k_wprep(
    const float* __restrict__ W1, const float* __restrict__ W2,
    const float* __restrict__ W3, ushort* __restrict__ TT) {
  int id = blockIdx.x * 256 + threadIdx.x;
  if (id < 32768) {                   // W1: k 0..255, n 0..127
    int k = id >> 7, n = id & 127;
    float v = W1[k * 128 + n];
    int half = k >> 7, kk = k & 127;
    ushort hi = f2bf_rne(v);
    TT[(half * 2 + 0) * 16384 + n * 128 + kk] = hi;
    TT[(half * 2 + 1) * 16384 + n * 128 + kk] = f2bf_rne(v - bf2f(hi));
  } else if (id < 49152) {            // W2
    int t = id - 32768;
    int k = t >> 7, n = t & 127;
    float v = W2[k * 128 + n];
    ushort hi = f2bf_rne(v);
    TT[4 * 16384 + n * 128 + k] = hi;
    TT[5 * 16384 + n * 128 + k] = f2bf_rne(v - bf2f(hi));
  } else if (id < 114688) {           // W3 hi only
    int s = id - 49152;
    int k = s >> 9, col = s & 511;
    int cb = col >> 7, n = col & 127;
    TT[(6 + cb) * 16384 + n * 128 + k] = f2bf_rne(W3[k * 512 + col]);
  }
}

// ---------------- K1: node up-projections ----------------------------------
__global__ __launch_bounds__(256) void k_node_up(
    const float* __restrict__ nf,
    const float* __restrict__ Wsc,
    const float* __restrict__ Wu0,
    const float* __restrict__ Wu1,
    ushort* __restrict__ NShi,
    ushort* __restrict__ NSlo,
    float* __restrict__ SU,
    float* __restrict__ VU)
{
  __shared__ float sIn[64][132];
  __shared__ float sW[128][128];
  const int n0 = blockIdx.x * 64;
  const int which = blockIdx.y;  // 0 NS(->bf16 hi/lo), 1 SU, 2..4 VU comp
  const float* W = (which == 0) ? Wsc : ((which == 1) ? Wu0 : Wu1);

  for (int idx = threadIdx.x; idx < 128 * 32; idx += 256) {
    int r = idx >> 5, fc = (idx & 31) << 2;
    *(float4*)&sW[r][fc] = *(const float4*)&W[r * 128 + fc];
  }
  if (which < 2) {
    for (int idx = threadIdx.x; idx < 64 * 32; idx += 256) {
      int r = idx >> 5, fc = (idx & 31) << 2;
      int n = n0 + r;
      float4 v = {0.f, 0.f, 0.f, 0.f};
      if (n < N_NODESC) v = *(const float4*)&nf[(size_t)n * 512 + fc];
      *(float4*)&sIn[r][fc] = v;
    }
  } else {
    int comp = which - 2;
    for (int idx = threadIdx.x; idx < 64 * 128; idx += 256) {
      int r = idx >> 7, u = idx & 127;
      int n = n0 + r;
      sIn[r][u] = (n < N_NODESC) ? nf[(size_t)n * 512 + 128 + u * 3 + comp] : 0.f;
    }
  }
  __syncthreads();

  const int r0 = (threadIdx.x >> 4) * 4;
  const int c0 = (threadIdx.x & 15) * 8;
  float acc[4][8] = {};
  #pragma unroll 4
  for (int k = 0; k < 128; k++) {
    float a[4];
    #pragma unroll
    for (int j = 0; j < 4; j++) a[j] = sIn[r0 + j][k];
    float w[8];
    *(float4*)&w[0] = *(const float4*)&sW[k][c0];
    *(float4*)&w[4] = *(const float4*)&sW[k][c0 + 4];
    #pragma unroll
    for (int j = 0; j < 4; j++)
      #pragma unroll
      for (int c = 0; c < 8; c++) acc[j][c] += a[j] * w[c];
  }
  #pragma unroll
  for (int j = 0; j < 4; j++) {
    int n = n0 + r0 + j;
    if (n < N_NODESC) {
      if (which == 0) {
        #pragma unroll
        for (int c = 0; c < 8; c++) {
          float o = acc[j][c] * INV128;
          ushort hi = f2bf_rne(o);
          NShi[(size_t)n * 128 + c0 + c] = hi;
          NSlo[(size_t)n * 128 + c0 + c] = f2bf_rne(o - bf2f(hi));
        }
      } else {
        float* out = (which == 1) ? SU : (VU + (size_t)(which - 2) * NP);
        float o[8];
        #pragma unroll
        for (int c = 0; c < 8; c++) o[c] = acc[j][c] * INV128;
        *(float4*)&out[(size_t)n * 128 + c0] = *(float4*)&o[0];
        *(float4*)&out[(size_t)n * 128 + c0 + 4] = *(float4*)&o[4];
      }
    }
  }
}

// ---------------- fused edge kernel (MFMA, async-staged weights) -----------
#define GEMM_PASS2(ACC)                                                        \
  _Pragma("unroll") for (int s = 0; s < 4; s++) {                              \
    bf16x8 ah = *(const bf16x8*)&sAh[ar][s * 32 + lq * 8];                     \
    bf16x8 al = *(const bf16x8*)&sAl[ar][s * 32 + lq * 8];                     \
    _Pragma("unroll") for (int nt = 0; nt < 8; nt++) {                         \
      bf16x8 bb = *(const bf16x8*)&sB[nt * 16 + ln][s * 32 + lq * 8];          \
      ACC[nt] = __builtin_amdgcn_mfma_f32_16x16x32_bf16(ah, bb, ACC[nt], 0, 0, 0); \
      ACC[nt] = __builtin_amdgcn_mfma_f32_16x16x32_bf16(al, bb, ACC[nt], 0, 0, 0); \
    }                                                                          \
  }

#define GEMM_PASS1(ACC)                                                        \
  _Pragma("unroll") for (int s = 0; s < 4; s++) {                              \
    bf16x8 ah = *(const bf16x8*)&sAh[ar][s * 32 + lq * 8];                     \
    _Pragma("unroll") for (int nt = 0; nt < 8; nt++) {                         \
      bf16x8 bb = *(const bf16x8*)&sB[nt * 16 + ln][s * 32 + lq * 8];          \
      ACC[nt] = __builtin_amdgcn_mfma_f32_16x16x32_bf16(ah, bb, ACC[nt], 0, 0, 0); \
    }                                                                          \
  }

#define PF_A(T) { _Pragma("unroll") for (int i = 0; i < 8; i++)                \
    rgA[i] = ttp[(T) * 2048 + cid + 256 * i]; }
#define PF_B(T) { _Pragma("unroll") for (int i = 0; i < 8; i++)                \
    rgB[i] = ttp[(T) * 2048 + cid + 256 * i]; }
#define SBW_A() { _Pragma("unroll") for (int i = 0; i < 8; i++) {              \
    int c = cid + 256 * i; *(uint4*)&sB[c >> 4][(c & 15) * 8] = rgA[i]; } }
#define SBW_B() { _Pragma("unroll") for (int i = 0; i < 8; i++) {              \
    int c = cid + 256 * i; *(uint4*)&sB[c >> 4][(c & 15) * 8] = rgB[i]; } }

#define STAGEA(USE_RCV)                                                        \
  for (int c = cid; c < 64 * 16; c += 256) {                                   \
    int r = c >> 4, o = c & 15;                                                \
    int n = (USE_RCV) ? sRcv[r] : sSnd[r];                                     \
    *(uint4*)&sAh[r][o * 8] = *(const uint4*)&NShi[(size_t)n * 128 + o * 8];   \
    *(uint4*)&sAl[r][o * 8] = *(const uint4*)&NSlo[(size_t)n * 128 + o * 8];   \
  }

// two-group segmented reduce: threads<128 do (PLO,MLO), others (PHI,MHI); -1 = idle
#define RED2(PLO, MLO, PHI, MHI) {                                             \
  __syncthreads();                                                             \
  {                                                                            \
    int pp = (cid < 128) ? (PLO) : (PHI);                                      \
    int mi = (cid < 128) ? (MLO) : (MHI);                                      \
    if (pp >= 0) {                                                             \
      int col = cid & 127;                                                     \
      float sum = 0.f; int prev = sRcv[0]; int segl = 0;                       \
      for (int e2 = 0; e2 < 64; e2++) {                                        \
        int rv = sRcv[e2];                                                     \
        if (rv != prev) {                                                      \
          if (segl == 0 && contF) CONT[(size_t)gblk * 1024 + pp * 128 + col] = sum; \
          else MSG[(size_t)pp * NP + (size_t)prev * 128 + col] = sum;          \
          prev = rv; segl = e2; sum = 0.f;                                     \
        }                                                                      \
        float mv = sMsg[e2][col];                                              \
        sum += (mi >= 0) ? mv * sY4[e2][mi] : mv;                              \
      }                                                                        \
      if (segl == 0 && contF) CONT[(size_t)gblk * 1024 + pp * 128 + col] = sum; \
      else MSG[(size_t)pp * NP + (size_t)prev * 128 + col] = sum;              \
    }                                                                          \
  }                                                                            \
  __syncthreads(); }

__global__ __launch_bounds__(256, 2) void k_edge_fused(
    const ushort* __restrict__ NShi,
    const ushort* __restrict__ NSlo,
    const float* __restrict__ SU,
    const float* __restrict__ VU,   // 3 planes
    const float* __restrict__ ef,
    const float* __restrict__ len,
    const float* __restrict__ ea,
    const int* __restrict__ eidx,
    const int* __restrict__ perm,
    const int* __restrict__ row_start,
    const float* __restrict__ W1,   // f32, for tail rows
    const float* __restrict__ b1,
    const float* __restrict__ b2,
    const ushort* __restrict__ TT,  // 10 prepped tiles
    float* __restrict__ MSG,        // 8 planes
    float* __restrict__ CONT)       // [NBLK_TOT][1024]
{
  __shared__ ushort sAh[64][136];
  __shared__ ushort sAl[64][136];
  __shared__ ushort sB[128][136];   // W tile during GEMM; f32 msg buffer in emit
  __shared__ float sT[11][128];     // W1 tail rows (9), b1, b2
  __shared__ float sEL[64][12];
  __shared__ float sY4[64][4];
  __shared__ int sSnd[64], sRcv[64];
  __shared__ int sContFirst;
  float (*sMsg)[132] = (float (*)[132])&sB[0][0];

  const int gblk = blockIdx.x;
  const int j0 = gblk * 64;
  const int cid = threadIdx.x;
  const int wid = cid >> 6;
  const int lane = cid & 63;
  const int lq = lane >> 4;
  const int ln = lane & 15;
  const int ar = wid * 16 + ln;
  const uint4* ttp = (const uint4*)TT;

  uint4 rgA[8], rgB[8];
  PF_A(0)

  if (cid < 64) {
    int r = cid;
    int e = perm[j0 + r];
    sSnd[r] = eidx[e];
    sRcv[r] = eidx[N_EDGESC + e];
    #pragma unroll
    for (int q = 0; q < 8; q++) sEL[r][q] = ef[(size_t)e * 8 + q];
    sEL[r][8] = len[e];
    *(float4*)&sY4[r][0] = *(const float4*)&ea[(size_t)e * 4];
    if (r == 0) sContFirst = (row_start[eidx[N_EDGESC + e]] != j0) ? 1 : 0;
  }
  for (int idx = cid; idx < 11 * 128; idx += 256) {
    int r = idx >> 7, c2 = idx & 127;
    sT[r][c2] = (r < 9) ? W1[(256 + r) * 128 + c2] : (r == 9 ? b1[c2] : b2[c2]);
  }
  __syncthreads();                       // B1: meta + sT
  const bool contF = (sContFirst != 0);

  // ---------- layer 1 ----------
  f32x4 acc[8];
  #pragma unroll
  for (int nt = 0; nt < 8; nt++) acc[nt] = (f32x4){0.f, 0.f, 0.f, 0.f};

  STAGEA(0)
  SBW_A()                                // t0
  __syncthreads();                       // B2
  PF_B(1)
  GEMM_PASS2(acc)
  __syncthreads();                       // B3
  SBW_B()                                // t1
  __syncthreads();                       // B4
  PF_A(2)
  GEMM_PASS1(acc)
  __syncthreads();                       // B5
  STAGEA(1)
  SBW_A()                                // t2
  __syncthreads();                       // B6
  PF_B(3)
  GEMM_PASS2(acc)
  __syncthreads();                       // B7
  SBW_B()                                // t3
  __syncthreads();                       // B8
  PF_A(4)
  GEMM_PASS1(acc)
  __syncthreads();                       // B9

  // tail + bias + silu -> h1 (bf16 hi/lo into sAh/sAl)
  #pragma unroll
  for (int q = 0; q < 4; q++) {
    int rr = wid * 16 + lq * 4 + q;
    float el[9];
    #pragma unroll
    for (int t = 0; t < 9; t++) el[t] = sEL[rr][t];
    #pragma unroll
    for (int nt = 0; nt < 8; nt++) {
      int col = nt * 16 + ln;
      float v = acc[nt][q] + sT[9][col];
      #pragma unroll
      for (int t = 0; t < 9; t++) v += el[t] * sT[t][col];
      float h = silu_f(v);
      ushort hi = f2bf_rne(h);
      sAh[rr][col] = hi;
      sAl[rr][col] = f2bf_rne(h - bf2f(hi));
    }
  }
  SBW_A()                                // t4
  __syncthreads();                       // B10

  // ---------- layer 2 ----------
  f32x4 acc2[8];
  #pragma unroll
  for (int nt = 0; nt < 8; nt++) acc2[nt] = (f32x4){0.f, 0.f, 0.f, 0.f};
  PF_B(5)
  GEMM_PASS2(acc2)
  __syncthreads();                       // B11
  SBW_B()                                // t5
  __syncthreads();                       // B12
  PF_A(6)
  GEMM_PASS1(acc2)
  __syncthreads();                       // B13
  #pragma unroll
  for (int q = 0; q < 4; q++) {
    int rr = wid * 16 + lq * 4 + q;
    #pragma unroll
    for (int nt = 0; nt < 8; nt++) {
      int col = nt * 16 + ln;
      float h = silu_f(acc2[nt][q] + sT[10][col]);
      ushort hi = f2bf_rne(h);
      sAh[rr][col] = hi;
      sAl[rr][col] = f2bf_rne(h - bf2f(hi));
    }
  }
  SBW_A()                                // t6
  __syncthreads();                       // B14

  // ---------- layer 3 chunks + emit + segmented reduce ----------
  int erow[4], esnd[4];
  float y0r[4], y1r3[4][3];
  #pragma unroll
  for (int q = 0; q < 4; q++) {
    int rr = wid * 16 + lq * 4 + q;
    erow[q] = rr;
    esnd[q] = sSnd[rr];
    y0r[q] = sY4[rr][0];
    #pragma unroll
    for (int i = 0; i < 3; i++) y1r3[q][i] = sY4[rr][1 + i];
  }
  float se[4][8];
  float dacc[4][8];

  // ----- cb0 (uses t6) -----
  {
    f32x4 acc3[8];
    #pragma unroll
    for (int nt = 0; nt < 8; nt++) acc3[nt] = (f32x4){0.f, 0.f, 0.f, 0.f};
    PF_B(7)
    GEMM_PASS2(acc3)
    __syncthreads();                     // sB free -> sMsg
    #pragma unroll
    for (int q = 0; q < 4; q++)
      #pragma unroll
      for (int nt = 0; nt < 8; nt++)
        se[q][nt] = SU[(size_t)esnd[q] * 128 + nt * 16 + ln];
    #pragma unroll
    for (int q = 0; q < 4; q++)
      #pragma unroll
      for (int nt = 0; nt < 8; nt++)
        sMsg[erow[q]][nt * 16 + ln] = acc3[nt][q] * se[q][nt] * y0r[q];
    RED2(0, -1, -1, -1)
    SBW_B()                              // t7
    __syncthreads();
  }
  // ----- cb1 (uses t7) -----
  {
    f32x4 acc3[8];
    #pragma unroll
    for (int nt = 0; nt < 8; nt++) acc3[nt] = (f32x4){0.f, 0.f, 0.f, 0.f};
    PF_A(8)
    GEMM_PASS2(acc3)
    __syncthreads();
    #pragma unroll
    for (int q = 0; q < 4; q++)
      #pragma unroll
      for (int nt = 0; nt < 8; nt++)
        sMsg[erow[q]][nt * 16 + ln] = acc3[nt][q] * se[q][nt];
    RED2(2, 1, 3, 2)
    RED2(4, 3, -1, -1)
    SBW_A()                              // t8
    __syncthreads();
  }
  // ----- cb2 (uses t8) -----
  {
    f32x4 acc3[8];
    #pragma unroll
    for (int nt = 0; nt < 8; nt++) acc3[nt] = (f32x4){0.f, 0.f, 0.f, 0.f};
    PF_B(9)
    GEMM_PASS2(acc3)
    __syncthreads();
    for (int pi = 0; pi < 3; pi++) {
      float vu[4][8];
      #pragma unroll
      for (int q = 0; q < 4; q++)
        #pragma unroll
        for (int nt = 0; nt < 8; nt++) {
          vu[q][nt] = VU[(size_t)pi * NP + (size_t)esnd[q] * 128 + nt * 16 + ln];
          if (pi == 0) dacc[q][nt] = vu[q][nt] * y1r3[q][0];
          else dacc[q][nt] += vu[q][nt] * y1r3[q][pi];
        }
      #pragma unroll
      for (int q = 0; q < 4; q++)
        #pragma unroll
        for (int nt = 0; nt < 8; nt++)
          sMsg[erow[q]][nt * 16 + ln] = acc3[nt][q] * vu[q][nt];
      if (pi == 0) { RED2(5, 0, -1, -1) }
      else if (pi == 1) { RED2(6, 0, -1, -1) }
      else { RED2(7, 0, -1, -1) }
    }
    SBW_B()                              // t9
    __syncthreads();
  }
  // ----- cb3 (uses t9) -----
  {
    f32x4 acc3[8];
    #pragma unroll
    for (int nt = 0; nt < 8; nt++) acc3[nt] = (f32x4){0.f, 0.f, 0.f, 0.f};
    GEMM_PASS2(acc3)
    __syncthreads();
    #pragma unroll
    for (int q = 0; q < 4; q++)
      #pragma unroll
      for (int nt = 0; nt < 8; nt++)
        sMsg[erow[q]][nt * 16 + ln] = acc3[nt][q] * dacc[q][nt] * INV_SQRT3C;
    RED2(1, -1, -1, -1)
  }
}

// ---------------- fixup: add continuation partials into MSG ----------------
__global__ __launch_bounds__(256) void k_fixup(float* __restrict__ MSG,
                                               const float* __restrict__ CONT,
                                               const int* __restrict__ row_start) {
  int t = blockIdx.x * 256 + threadIdx.x;
  int n = t >> 5;
  int c4 = (t & 31) * 4;
  if (n >= N_NODESC) return;
  int s = row_start[n], e = row_start[n + 1];
  if (e <= s) return;
  int b0 = s >> 6, b1 = (e - 1) >> 6;
  if (b1 <= b0) return;
  for (int p = 0; p < 8; p++) {
    float4 v = *(float4*)&MSG[(size_t)p * NP + (size_t)n * 128 + c4];
    for (int b = b0 + 1; b <= b1; b++) {
      const float4 u = *(const float4*)&CONT[(size_t)b * 1024 + p * 128 + c4];
      v.x += u.x; v.y += u.y; v.z += u.z; v.w += u.w;
    }
    *(float4*)&MSG[(size_t)p * NP + (size_t)n * 128 + c4] = v;
  }
}

// ---------------- K4: output GEMMs ----------------------------------------
__global__ __launch_bounds__(256) void k_out(
    const float* __restrict__ MSG,
    const float* __restrict__ Wo0,
    const float* __restrict__ Wo1,
    float* __restrict__ out)
{
  __shared__ float sA[64][132];
  __shared__ float sB2[64][132];
  __shared__ float sW[64][128];
  const int n0 = blockIdx.x * 64;
  const int y = blockIdx.y;
  const float* W = (y == 0) ? Wo0 : Wo1;
  const float* pA = MSG + (size_t)((y == 0) ? 0 : (1 + y)) * NP;
  const float* pB = MSG + (size_t)((y == 0) ? 1 : (4 + y)) * NP;

  for (int idx = threadIdx.x; idx < 64 * 32; idx += 256) {
    int r = idx >> 5, fc = (idx & 31) << 2;
    int n = n0 + r;
    float4 va = {0.f, 0.f, 0.f, 0.f}, vb = {0.f, 0.f, 0.f, 0.f};
    if (n < N_NODESC) {
      va = *(const float4*)&pA[(size_t)n * 128 + fc];
      vb = *(const float4*)&pB[(size_t)n * 128 + fc];
    }
    *(float4*)&sA[r][fc] = va;
    *(float4*)&sB2[r][fc] = vb;
  }
  const int r0 = (threadIdx.x >> 4) * 4;
  const int c0 = (threadIdx.x & 15) * 8;
  float acc[4][8] = {};
  for (int kc = 0; kc < 4; kc++) {
    __syncthreads();
    for (int idx = threadIdx.x; idx < 64 * 32; idx += 256) {
      int r = idx >> 5, fc = (idx & 31) << 2;
      *(float4*)&sW[r][fc] = *(const float4*)&W[(kc * 64 + r) * 128 + fc];
    }
    __syncthreads();
    const float (*sIn)[132] = (kc < 2) ? sA : sB2;
    const int kof = (kc & 1) * 64;
    #pragma unroll 4
    for (int k = 0; k < 64; k++) {
      float a[4];
      #pragma unroll
      for (int j = 0; j < 4; j++) a[j] = sIn[r0 + j][kof + k];
      float w[8];
      *(float4*)&w[0] = *(const float4*)&sW[k][c0];
      *(float4*)&w[4] = *(const float4*)&sW[k][c0 + 4];
      #pragma unroll
      for (int j = 0; j < 4; j++)
        #pragma unroll
        for (int c = 0; c < 8; c++) acc[j][c] += a[j] * w[c];
    }
  }
  #pragma unroll
  for (int j = 0; j < 4; j++) {
    int n = n0 + r0 + j;
    if (n < N_NODESC) {
      #pragma unroll
      for (int c = 0; c < 8; c++)
        out[(size_t)n * 512 + (size_t)(c0 + c) * 4 + y] = acc[j][c] * SCALE_OUT;
    }
  }
}

extern "C" void kernel_launch(void* const* d_in, const int* in_sizes, int n_in,
                              void* d_out, int out_size, void* d_ws, size_t ws_size,
                              hipStream_t stream) {
  const float* nf  = (const float*)d_in[0];
  const float* ea  = (const float*)d_in[1];
  const float* ef  = (const float*)d_in[2];
  const float* len = (const float*)d_in[3];
  const int*   ei  = (const int*)d_in[4];
  const float* Wsc = (const float*)d_in[5];
  const float* Wu0 = (const float*)d_in[6];
  const float* Wu1 = (const float*)d_in[7];
  const float* W1  = (const float*)d_in[8];
  const float* b1  = (const float*)d_in[9];
  const float* W2  = (const float*)d_in[10];
  const float* b2  = (const float*)d_in[11];
  const float* W3  = (const float*)d_in[12];
  const float* Wo0 = (const float*)d_in[13];
  const float* Wo1 = (const float*)d_in[14];
  float* out = (float*)d_out;
  float* ws  = (float*)d_ws;

  const size_t NPs = (size_t)NP;
  float* SU   = ws;                            // 1 plane
  float* VU   = ws + NPs;                      // 3 planes
  float* MSG  = ws + 4 * NPs;                  // 8 planes
  float* CONT = ws + 12 * NPs;                 // NBLK_TOT*1024
  ushort* NShi = (ushort*)(CONT + (size_t)NBLK_TOT * 1024);
  ushort* NSlo = NShi + NPs;
  ushort* TT   = NSlo + NPs;                   // 10*16384 ushorts
  int* perm      = (int*)(TT + 10 * 16384);
  int* deg       = perm + N_EDGESC;
  int* cursor    = deg + N_NODESC;
  int* row_start = cursor + N_NODESC;          // N_NODESC+1 ints

  hipMemsetAsync(deg, 0, N_NODESC * sizeof(int), stream);
  hipMemsetAsync(cursor, 0, N_NODESC * sizeof(int), stream);
  hipMemsetAsync(MSG, 0, 8 * NPs * sizeof(float), stream);

  k_hist<<<(N_EDGESC + 255) / 256, 256, 0, stream>>>(ei, deg);
  k_scan<<<1, 1024, 0, stream>>>(deg, row_start);
  k_scatter<<<(N_EDGESC + 255) / 256, 256, 0, stream>>>(ei, row_start, cursor, perm);
  k_sortseg<<<(N_NODESC + 255) / 256, 256, 0, stream>>>(perm, row_start);
  k_wprep<<<448, 256, 0, stream>>>(W1, W2, W3, TT);

  k_node_up<<<dim3(157, 5), 256, 0, stream>>>(nf, Wsc, Wu0, Wu1, NShi, NSlo, SU, VU);

  k_edge_fused<<<NBLK_TOT, 256, 0, stream>>>(NShi, NSlo, SU, VU, ef, len, ea, ei,
                                             perm, row_start, W1, b1, b2, TT,
                                             MSG, CONT);

  k_fixup<<<(N_NODESC * 32 + 255) / 256, 256, 0, stream>>>(MSG, CONT, row_start);
  k_out<<<dim3(157, 4), 256, 0, stream>>>(MSG, Wo0, Wo1, out);
}

// Round 6
// 507.821 us; speedup vs baseline: 10.1581x; 1.4396x over previous
//
#include <hip/hip_runtime.h>

#define N_NODESC 10000
#define N_EDGESC 160000
#define NBLK_TOT 2500                 // N_EDGESC/64
#define NP       (N_NODESC*128)       // plane size (floats)
#define INV128   0.08838834764831845f // 1/sqrt(128)
#define INV_SQRT3C 0.5773502691896258f
#define SCALE_OUT 0.00390625f         // (1/sqrt(256))/16

typedef __attribute__((ext_vector_type(8))) short bf16x8;
typedef __attribute__((ext_vector_type(4))) float f32x4;

__device__ __forceinline__ float silu_f(float x) {
  return x / (1.f + __expf(-x));
}
__device__ __forceinline__ ushort f2bf_rne(float x) {
  uint u = __float_as_uint(x);
  uint r = (u + 0x7FFFu + ((u >> 16) & 1u)) >> 16;
  return (ushort)r;
}
__device__ __forceinline__ float bf2f(ushort h) {
  return __uint_as_float(((uint)h) << 16);
}

// ---------------- CSR build ------------------------------------------------
__global__ __launch_bounds__(256) void k_hist(const int* __restrict__ eidx,
                                              int* __restrict__ deg) {
  int e = blockIdx.x * 256 + threadIdx.x;
  if (e < N_EDGESC) atomicAdd(&deg[eidx[N_EDGESC + e]], 1);
}

__global__ __launch_bounds__(1024) void k_scan(const int* __restrict__ deg,
                                               int* __restrict__ row_start) {
  __shared__ int buf[1024];
  const int t = threadIdx.x;
  int d[10];
  int loc = 0;
  #pragma unroll
  for (int i = 0; i < 10; i++) {
    int n = t * 10 + i;
    d[i] = (n < N_NODESC) ? deg[n] : 0;
    loc += d[i];
  }
  buf[t] = loc;
  __syncthreads();
  int v = loc;
  for (int off = 1; off < 1024; off <<= 1) {
    int u = (t >= off) ? buf[t - off] : 0;
    __syncthreads();
    v += u;
    buf[t] = v;
    __syncthreads();
  }
  int run = v - loc;
  #pragma unroll
  for (int i = 0; i < 10; i++) {
    int n = t * 10 + i;
    if (n < N_NODESC) row_start[n] = run;
    run += d[i];
  }
  if (t == 1023) row_start[N_NODESC] = v;
}

__global__ __launch_bounds__(256) void k_scatter(const int* __restrict__ eidx,
                                                 const int* __restrict__ row_start,
                                                 int* __restrict__ cursor,
                                                 int* __restrict__ perm) {
  int e = blockIdx.x * 256 + threadIdx.x;
  if (e < N_EDGESC) {
    int r = eidx[N_EDGESC + e];
    int pos = row_start[r] + atomicAdd(&cursor[r], 1);
    perm[pos] = e;
  }
}

__global__ __launch_bounds__(256) void k_sortseg(int* __restrict__ perm,
                                                 const int* __restrict__ row_start) {
  int n = blockIdx.x * 256 + threadIdx.x;
  if (n >= N_NODESC) return;
  int s = row_start[n], e = row_start[n + 1];
  for (int i = s + 1; i < e; i++) {
    int key = perm[i];
    int j = i - 1;
    while (j >= s && perm[j] > key) { perm[j + 1] = perm[j]; j--; }
    perm[j + 1] = key;
  }
}

// ---------------- weight prep: tile-linear staging buffer ------------------
// TT tiles (each [128 n][128 k] bf16, 32KB), in stage order:
// t0 W1.k0-127.hi  t1 W1.k0-127.lo  t2 W1.k128-255.hi  t3 W1.k128-255.lo
// t4 W2.hi  t5 W2.lo  t6..t9 W3.cb0..cb3.hi (2-term: no W3 lo)
__global__ __launch_bounds__(256) void k_wprep(
    const float* __restrict__ W1, const float* __restrict__ W2,
    const float* __restrict__ W3, ushort* __restrict__ TT) {
  int id = blockIdx.x * 256 + threadIdx.x;
  if (id < 32768) {                   // W1: k 0..255, n 0..127
    int k = id >> 7, n = id & 127;
    float v = W1[k * 128 + n];
    int half = k >> 7, kk = k & 127;
    ushort hi = f2bf_rne(v);
    TT[(half * 2 + 0) * 16384 + n * 128 + kk] = hi;
    TT[(half * 2 + 1) * 16384 + n * 128 + kk] = f2bf_rne(v - bf2f(hi));
  } else if (id < 49152) {            // W2
    int t = id - 32768;
    int k = t >> 7, n = t & 127;
    float v = W2[k * 128 + n];
    ushort hi = f2bf_rne(v);
    TT[4 * 16384 + n * 128 + k] = hi;
    TT[5 * 16384 + n * 128 + k] = f2bf_rne(v - bf2f(hi));
  } else if (id < 114688) {           // W3 hi only
    int s = id - 49152;
    int k = s >> 9, col = s & 511;
    int cb = col >> 7, n = col & 127;
    TT[(6 + cb) * 16384 + n * 128 + k] = f2bf_rne(W3[k * 512 + col]);
  }
}

// ---------------- K1: node up-projections ----------------------------------
__global__ __launch_bounds__(256) void k_node_up(
    const float* __restrict__ nf,
    const float* __restrict__ Wsc,
    const float* __restrict__ Wu0,
    const float* __restrict__ Wu1,
    ushort* __restrict__ NShi,
    ushort* __restrict__ NSlo,
    float* __restrict__ SU,
    float* __restrict__ VU)
{
  __shared__ float sIn[64][132];
  __shared__ float sW[128][128];
  const int n0 = blockIdx.x * 64;
  const int which = blockIdx.y;  // 0 NS(->bf16 hi/lo), 1 SU, 2..4 VU comp
  const float* W = (which == 0) ? Wsc : ((which == 1) ? Wu0 : Wu1);

  for (int idx = threadIdx.x; idx < 128 * 32; idx += 256) {
    int r = idx >> 5, fc = (idx & 31) << 2;
    *(float4*)&sW[r][fc] = *(const float4*)&W[r * 128 + fc];
  }
  if (which < 2) {
    for (int idx = threadIdx.x; idx < 64 * 32; idx += 256) {
      int r = idx >> 5, fc = (idx & 31) << 2;
      int n = n0 + r;
      float4 v = {0.f, 0.f, 0.f, 0.f};
      if (n < N_NODESC) v = *(const float4*)&nf[(size_t)n * 512 + fc];
      *(float4*)&sIn[r][fc] = v;
    }
  } else {
    int comp = which - 2;
    for (int idx = threadIdx.x; idx < 64 * 128; idx += 256) {
      int r = idx >> 7, u = idx & 127;
      int n = n0 + r;
      sIn[r][u] = (n < N_NODESC) ? nf[(size_t)n * 512 + 128 + u * 3 + comp] : 0.f;
    }
  }
  __syncthreads();

  const int r0 = (threadIdx.x >> 4) * 4;
  const int c0 = (threadIdx.x & 15) * 8;
  float acc[4][8] = {};
  #pragma unroll 4
  for (int k = 0; k < 128; k++) {
    float a[4];
    #pragma unroll
    for (int j = 0; j < 4; j++) a[j] = sIn[r0 + j][k];
    float w[8];
    *(float4*)&w[0] = *(const float4*)&sW[k][c0];
    *(float4*)&w[4] = *(const float4*)&sW[k][c0 + 4];
    #pragma unroll
    for (int j = 0; j < 4; j++)
      #pragma unroll
      for (int c = 0; c < 8; c++) acc[j][c] += a[j] * w[c];
  }
  #pragma unroll
  for (int j = 0; j < 4; j++) {
    int n = n0 + r0 + j;
    if (n < N_NODESC) {
      if (which == 0) {
        #pragma unroll
        for (int c = 0; c < 8; c++) {
          float o = acc[j][c] * INV128;
          ushort hi = f2bf_rne(o);
          NShi[(size_t)n * 128 + c0 + c] = hi;
          NSlo[(size_t)n * 128 + c0 + c] = f2bf_rne(o - bf2f(hi));
        }
      } else {
        float* out = (which == 1) ? SU : (VU + (size_t)(which - 2) * NP);
        float o[8];
        #pragma unroll
        for (int c = 0; c < 8; c++) o[c] = acc[j][c] * INV128;
        *(float4*)&out[(size_t)n * 128 + c0] = *(float4*)&o[0];
        *(float4*)&out[(size_t)n * 128 + c0 + 4] = *(float4*)&o[4];
      }
    }
  }
}

// ---------------- fused edge kernel (MFMA split-bf16) ----------------------
#define GEMM_PASS2(ACC)                                                        \
  _Pragma("unroll") for (int s = 0; s < 4; s++) {                              \
    bf16x8 ah = *(const bf16x8*)&sAh[ar][s * 32 + lq * 8];                     \
    bf16x8 al = *(const bf16x8*)&sAl[ar][s * 32 + lq * 8];                     \
    _Pragma("unroll") for (int nt = 0; nt < 8; nt++) {                         \
      bf16x8 bb = *(const bf16x8*)&sB[nt * 16 + ln][s * 32 + lq * 8];          \
      ACC[nt] = __builtin_amdgcn_mfma_f32_16x16x32_bf16(ah, bb, ACC[nt], 0, 0, 0); \
      ACC[nt] = __builtin_amdgcn_mfma_f32_16x16x32_bf16(al, bb, ACC[nt], 0, 0, 0); \
    }                                                                          \
  }

#define GEMM_PASS1(ACC)                                                        \
  _Pragma("unroll") for (int s = 0; s < 4; s++) {                              \
    bf16x8 ah = *(const bf16x8*)&sAh[ar][s * 32 + lq * 8];                     \
    _Pragma("unroll") for (int nt = 0; nt < 8; nt++) {                         \
      bf16x8 bb = *(const bf16x8*)&sB[nt * 16 + ln][s * 32 + lq * 8];          \
      ACC[nt] = __builtin_amdgcn_mfma_f32_16x16x32_bf16(ah, bb, ACC[nt], 0, 0, 0); \
    }                                                                          \
  }

// transient staging: load whole tile to short-lived regs, write to LDS
#define STAGEB(T) { uint4 tv[8];                                               \
  _Pragma("unroll") for (int i = 0; i < 8; i++)                                \
    tv[i] = ttp[(T) * 2048 + cid + 256 * i];                                   \
  _Pragma("unroll") for (int i = 0; i < 8; i++) {                              \
    int c = cid + 256 * i;                                                     \
    *(uint4*)&sB[c >> 4][(c & 15) * 8] = tv[i]; } }

#define STAGEA(USE_RCV)                                                        \
  for (int c = cid; c < 64 * 16; c += 256) {                                   \
    int r = c >> 4, o = c & 15;                                                \
    int n = (USE_RCV) ? sRcv[r] : sSnd[r];                                     \
    *(uint4*)&sAh[r][o * 8] = *(const uint4*)&NShi[(size_t)n * 128 + o * 8];   \
    *(uint4*)&sAl[r][o * 8] = *(const uint4*)&NSlo[(size_t)n * 128 + o * 8];   \
  }

// parallel segmented reduce: tasks = nseg x 128 cols, 4-batched loads,
// sequential ascending adds within segment (deterministic).
#define REDUCE(P, MI) {                                                        \
  const int nseg128 = sNseg << 7;                                              \
  for (int task = cid; task < nseg128; task += 256) {                          \
    const int si = task >> 7, col = task & 127;                                \
    const int s = sSegStart[si], e = sSegStart[si + 1];                        \
    float sum = 0.f;                                                           \
    int e2 = s;                                                                \
    for (; e2 + 4 <= e; e2 += 4) {                                             \
      float m0 = sMsg[e2][col],     m1 = sMsg[e2 + 1][col];                    \
      float m2 = sMsg[e2 + 2][col], m3 = sMsg[e2 + 3][col];                    \
      if ((MI) >= 0) {                                                         \
        const int mi = (MI) >= 0 ? (MI) : 0;                                   \
        sum += m0 * sY4[e2][mi];     sum += m1 * sY4[e2 + 1][mi];              \
        sum += m2 * sY4[e2 + 2][mi]; sum += m3 * sY4[e2 + 3][mi];              \
      } else { sum += m0; sum += m1; sum += m2; sum += m3; }                   \
    }                                                                          \
    for (; e2 < e; e2++) {                                                     \
      float mv = sMsg[e2][col];                                                \
      sum += ((MI) >= 0) ? mv * sY4[e2][(MI) >= 0 ? (MI) : 0] : mv;            \
    }                                                                          \
    if (si == 0 && contF)                                                      \
      CONT[(size_t)gblk * 1024 + (P) * 128 + col] = sum;                       \
    else                                                                       \
      MSG[(size_t)(P) * NP + (size_t)sRcv[s] * 128 + col] = sum;               \
  } }

__global__ __launch_bounds__(256, 2) void k_edge_fused(
    const ushort* __restrict__ NShi,
    const ushort* __restrict__ NSlo,
    const float* __restrict__ SU,
    const float* __restrict__ VU,   // 3 planes
    const float* __restrict__ ef,
    const float* __restrict__ len,
    const float* __restrict__ ea,
    const int* __restrict__ eidx,
    const int* __restrict__ perm,
    const int* __restrict__ row_start,
    const float* __restrict__ W1,   // f32, for tail rows
    const float* __restrict__ b1,
    const float* __restrict__ b2,
    const ushort* __restrict__ TT,  // 10 prepped tiles
    float* __restrict__ MSG,        // 8 planes
    float* __restrict__ CONT)       // [NBLK_TOT][1024]
{
  __shared__ ushort sAh[64][136];
  __shared__ ushort sAl[64][136];
  __shared__ ushort sB[128][136];   // W tile during GEMM; f32 msg buffer in emit
  __shared__ float sT[11][128];     // W1 tail rows (9), b1, b2
  __shared__ float sEL[64][10];
  __shared__ float sY4[64][4];
  __shared__ int sSnd[64], sRcv[64];
  __shared__ int sSegStart[65];
  __shared__ int sNseg;
  __shared__ int sContFirst;
  float (*sMsg)[132] = (float (*)[132])&sB[0][0];

  const int gblk = blockIdx.x;
  const int j0 = gblk * 64;
  const int cid = threadIdx.x;
  const int wid = cid >> 6;
  const int lane = cid & 63;
  const int lq = lane >> 4;
  const int ln = lane & 15;
  const int ar = wid * 16 + ln;
  const uint4* ttp = (const uint4*)TT;

  if (cid < 64) {
    int r = cid;
    int e = perm[j0 + r];
    sSnd[r] = eidx[e];
    sRcv[r] = eidx[N_EDGESC + e];
    #pragma unroll
    for (int q = 0; q < 8; q++) sEL[r][q] = ef[(size_t)e * 8 + q];
    sEL[r][8] = len[e];
    *(float4*)&sY4[r][0] = *(const float4*)&ea[(size_t)e * 4];
    if (r == 0) sContFirst = (row_start[eidx[N_EDGESC + e]] != j0) ? 1 : 0;
  }
  for (int idx = cid; idx < 11 * 128; idx += 256) {
    int r = idx >> 7, c2 = idx & 127;
    sT[r][c2] = (r < 9) ? W1[(256 + r) * 128 + c2] : (r == 9 ? b1[c2] : b2[c2]);
  }
  __syncthreads();                       // B1: meta + sT
  const bool contF = (sContFirst != 0);

  // segment list via wave ballot (wave 0 only; lanes = edges)
  if (cid < 64) {
    int r = cid;
    bool flag = (r == 0) || (sRcv[r] != sRcv[r - 1]);
    unsigned long long mask = __ballot(flag ? 1 : 0);
    if (flag) {
      int rank = __popcll(mask & ((1ull << r) - 1ull));
      sSegStart[rank] = r;
    }
    if (r == 0) sNseg = __popcll(mask);
    if (r == 63) sSegStart[__popcll(mask)] = 64;
  }

  // ---------- layer 1 (K=256 as two 128-halves, 3-term split) ----------
  f32x4 acc[8];
  #pragma unroll
  for (int nt = 0; nt < 8; nt++) acc[nt] = (f32x4){0.f, 0.f, 0.f, 0.f};

  STAGEA(0)
  STAGEB(0)
  __syncthreads();
  GEMM_PASS2(acc)
  __syncthreads();
  STAGEB(1)
  __syncthreads();
  GEMM_PASS1(acc)
  __syncthreads();
  STAGEA(1)
  STAGEB(2)
  __syncthreads();
  GEMM_PASS2(acc)
  __syncthreads();
  STAGEB(3)
  __syncthreads();
  GEMM_PASS1(acc)
  __syncthreads();

  // tail + bias + silu -> h1 (bf16 hi/lo into sAh/sAl)
  #pragma unroll
  for (int q = 0; q < 4; q++) {
    int rr = wid * 16 + lq * 4 + q;
    float el[9];
    #pragma unroll
    for (int t = 0; t < 9; t++) el[t] = sEL[rr][t];
    #pragma unroll
    for (int nt = 0; nt < 8; nt++) {
      int col = nt * 16 + ln;
      float v = acc[nt][q] + sT[9][col];
      #pragma unroll
      for (int t = 0; t < 9; t++) v += el[t] * sT[t][col];
      float h = silu_f(v);
      ushort hi = f2bf_rne(h);
      sAh[rr][col] = hi;
      sAl[rr][col] = f2bf_rne(h - bf2f(hi));
    }
  }
  STAGEB(4)
  __syncthreads();

  // ---------- layer 2 ----------
  f32x4 acc2[8];
  #pragma unroll
  for (int nt = 0; nt < 8; nt++) acc2[nt] = (f32x4){0.f, 0.f, 0.f, 0.f};
  GEMM_PASS2(acc2)
  __syncthreads();
  STAGEB(5)
  __syncthreads();
  GEMM_PASS1(acc2)
  __syncthreads();
  #pragma unroll
  for (int q = 0; q < 4; q++) {
    int rr = wid * 16 + lq * 4 + q;
    #pragma unroll
    for (int nt = 0; nt < 8; nt++) {
      int col = nt * 16 + ln;
      float h = silu_f(acc2[nt][q] + sT[10][col]);
      ushort hi = f2bf_rne(h);
      sAh[rr][col] = hi;
      sAl[rr][col] = f2bf_rne(h - bf2f(hi));
    }
  }
  STAGEB(6)
  __syncthreads();

  // ---------- layer 3 chunks + emit + parallel segmented reduce ----------
  int erow[4], esnd[4];
  float y0r[4], y1r3[4][3];
  #pragma unroll
  for (int q = 0; q < 4; q++) {
    int rr = wid * 16 + lq * 4 + q;
    erow[q] = rr;
    esnd[q] = sSnd[rr];
    y0r[q] = sY4[rr][0];
    #pragma unroll
    for (int i = 0; i < 3; i++) y1r3[q][i] = sY4[rr][1 + i];
  }
  float se[4][8];
  float dacc[4][8];

  // ----- cb0 (tile t6) -----
  {
    f32x4 acc3[8];
    #pragma unroll
    for (int nt = 0; nt < 8; nt++) acc3[nt] = (f32x4){0.f, 0.f, 0.f, 0.f};
    GEMM_PASS2(acc3)
    __syncthreads();                     // sB free -> sMsg
    #pragma unroll
    for (int q = 0; q < 4; q++)
      #pragma unroll
      for (int nt = 0; nt < 8; nt++)
        se[q][nt] = SU[(size_t)esnd[q] * 128 + nt * 16 + ln];
    #pragma unroll
    for (int q = 0; q < 4; q++)
      #pragma unroll
      for (int nt = 0; nt < 8; nt++)
        sMsg[erow[q]][nt * 16 + ln] = acc3[nt][q] * se[q][nt] * y0r[q];
    __syncthreads();
    REDUCE(0, -1)
    __syncthreads();
    STAGEB(7)
    __syncthreads();
  }
  // ----- cb1 (tile t7) -----
  {
    f32x4 acc3[8];
    #pragma unroll
    for (int nt = 0; nt < 8; nt++) acc3[nt] = (f32x4){0.f, 0.f, 0.f, 0.f};
    GEMM_PASS2(acc3)
    __syncthreads();
    #pragma unroll
    for (int q = 0; q < 4; q++)
      #pragma unroll
      for (int nt = 0; nt < 8; nt++)
        sMsg[erow[q]][nt * 16 + ln] = acc3[nt][q] * se[q][nt];
    __syncthreads();
    REDUCE(2, 1)
    REDUCE(3, 2)
    REDUCE(4, 3)
    __syncthreads();
    STAGEB(8)
    __syncthreads();
  }
  // ----- cb2 (tile t8) -----
  {
    f32x4 acc3[8];
    #pragma unroll
    for (int nt = 0; nt < 8; nt++) acc3[nt] = (f32x4){0.f, 0.f, 0.f, 0.f};
    GEMM_PASS2(acc3)
    __syncthreads();
    for (int pi = 0; pi < 3; pi++) {
      float vu[4][8];
      #pragma unroll
      for (int q = 0; q < 4; q++)
        #pragma unroll
        for (int nt = 0; nt < 8; nt++) {
          vu[q][nt] = VU[(size_t)pi * NP + (size_t)esnd[q] * 128 + nt * 16 + ln];
          if (pi == 0) dacc[q][nt] = vu[q][nt] * y1r3[q][0];
          else dacc[q][nt] += vu[q][nt] * y1r3[q][pi];
        }
      #pragma unroll
      for (int q = 0; q < 4; q++)
        #pragma unroll
        for (int nt = 0; nt < 8; nt++)
          sMsg[erow[q]][nt * 16 + ln] = acc3[nt][q] * vu[q][nt];
      __syncthreads();
      if (pi == 0) { REDUCE(5, 0) }
      else if (pi == 1) { REDUCE(6, 0) }
      else { REDUCE(7, 0) }
      __syncthreads();
    }
    STAGEB(9)
    __syncthreads();
  }
  // ----- cb3 (tile t9) -----
  {
    f32x4 acc3[8];
    #pragma unroll
    for (int nt = 0; nt < 8; nt++) acc3[nt] = (f32x4){0.f, 0.f, 0.f, 0.f};
    GEMM_PASS2(acc3)
    __syncthreads();
    #pragma unroll
    for (int q = 0; q < 4; q++)
      #pragma unroll
      for (int nt = 0; nt < 8; nt++)
        sMsg[erow[q]][nt * 16 + ln] = acc3[nt][q] * dacc[q][nt] * INV_SQRT3C;
    __syncthreads();
    REDUCE(1, -1)
  }
}

// ---------------- fixup: add continuation partials into MSG ----------------
__global__ __launch_bounds__(256) void k_fixup(float* __restrict__ MSG,
                                               const float* __restrict__ CONT,
                                               const int* __restrict__ row_start) {
  int t = blockIdx.x * 256 + threadIdx.x;
  int n = t >> 5;
  int c4 = (t & 31) * 4;
  if (n >= N_NODESC) return;
  int s = row_start[n], e = row_start[n + 1];
  if (e <= s) return;
  int b0 = s >> 6, b1 = (e - 1) >> 6;
  if (b1 <= b0) return;
  for (int p = 0; p < 8; p++) {
    float4 v = *(float4*)&MSG[(size_t)p * NP + (size_t)n * 128 + c4];
    for (int b = b0 + 1; b <= b1; b++) {
      const float4 u = *(const float4*)&CONT[(size_t)b * 1024 + p * 128 + c4];
      v.x += u.x; v.y += u.y; v.z += u.z; v.w += u.w;
    }
    *(float4*)&MSG[(size_t)p * NP + (size_t)n * 128 + c4] = v;
  }
}

// ---------------- K4: output GEMMs ----------------------------------------
__global__ __launch_bounds__(256) void k_out(
    const float* __restrict__ MSG,
    const float* __restrict__ Wo0,
    const float* __restrict__ Wo1,
    float* __restrict__ out)
{
  __shared__ float sA[64][132];
  __shared__ float sB2[64][132];
  __shared__ float sW[64][128];
  const int n0 = blockIdx.x * 64;
  const int y = blockIdx.y;
  const float* W = (y == 0) ? Wo0 : Wo1;
  const float* pA = MSG + (size_t)((y == 0) ? 0 : (1 + y)) * NP;
  const float* pB = MSG + (size_t)((y == 0) ? 1 : (4 + y)) * NP;

  for (int idx = threadIdx.x; idx < 64 * 32; idx += 256) {
    int r = idx >> 5, fc = (idx & 31) << 2;
    int n = n0 + r;
    float4 va = {0.f, 0.f, 0.f, 0.f}, vb = {0.f, 0.f, 0.f, 0.f};
    if (n < N_NODESC) {
      va = *(const float4*)&pA[(size_t)n * 128 + fc];
      vb = *(const float4*)&pB[(size_t)n * 128 + fc];
    }
    *(float4*)&sA[r][fc] = va;
    *(float4*)&sB2[r][fc] = vb;
  }
  const int r0 = (threadIdx.x >> 4) * 4;
  const int c0 = (threadIdx.x & 15) * 8;
  float acc[4][8] = {};
  for (int kc = 0; kc < 4; kc++) {
    __syncthreads();
    for (int idx = threadIdx.x; idx < 64 * 32; idx += 256) {
      int r = idx >> 5, fc = (idx & 31) << 2;
      *(float4*)&sW[r][fc] = *(const float4*)&W[(kc * 64 + r) * 128 + fc];
    }
    __syncthreads();
    const float (*sIn)[132] = (kc < 2) ? sA : sB2;
    const int kof = (kc & 1) * 64;
    #pragma unroll 4
    for (int k = 0; k < 64; k++) {
      float a[4];
      #pragma unroll
      for (int j = 0; j < 4; j++) a[j] = sIn[r0 + j][kof + k];
      float w[8];
      *(float4*)&w[0] = *(const float4*)&sW[k][c0];
      *(float4*)&w[4] = *(const float4*)&sW[k][c0 + 4];
      #pragma unroll
      for (int j = 0; j < 4; j++)
        #pragma unroll
        for (int c = 0; c < 8; c++) acc[j][c] += a[j] * w[c];
    }
  }
  #pragma unroll
  for (int j = 0; j < 4; j++) {
    int n = n0 + r0 + j;
    if (n < N_NODESC) {
      #pragma unroll
      for (int c = 0; c < 8; c++)
        out[(size_t)n * 512 + (size_t)(c0 + c) * 4 + y] = acc[j][c] * SCALE_OUT;
    }
  }
}

extern "C" void kernel_launch(void* const* d_in, const int* in_sizes, int n_in,
                              void* d_out, int out_size, void* d_ws, size_t ws_size,
                              hipStream_t stream) {
  const float* nf  = (const float*)d_in[0];
  const float* ea  = (const float*)d_in[1];
  const float* ef  = (const float*)d_in[2];
  const float* len = (const float*)d_in[3];
  const int*   ei  = (const int*)d_in[4];
  const float* Wsc = (const float*)d_in[5];
  const float* Wu0 = (const float*)d_in[6];
  const float* Wu1 = (const float*)d_in[7];
  const float* W1  = (const float*)d_in[8];
  const float* b1  = (const float*)d_in[9];
  const float* W2  = (const float*)d_in[10];
  const float* b2  = (const float*)d_in[11];
  const float* W3  = (const float*)d_in[12];
  const float* Wo0 = (const float*)d_in[13];
  const float* Wo1 = (const float*)d_in[14];
  float* out = (float*)d_out;
  float* ws  = (float*)d_ws;

  const size_t NPs = (size_t)NP;
  float* SU   = ws;                            // 1 plane
  float* VU   = ws + NPs;                      // 3 planes
  float* MSG  = ws + 4 * NPs;                  // 8 planes
  float* CONT = ws + 12 * NPs;                 // NBLK_TOT*1024
  ushort* NShi = (ushort*)(CONT + (size_t)NBLK_TOT * 1024);
  ushort* NSlo = NShi + NPs;
  ushort* TT   = NSlo + NPs;                   // 10*16384 ushorts
  int* perm      = (int*)(TT + 10 * 16384);
  int* deg       = perm + N_EDGESC;
  int* cursor    = deg + N_NODESC;
  int* row_start = cursor + N_NODESC;          // N_NODESC+1 ints

  hipMemsetAsync(deg, 0, N_NODESC * sizeof(int), stream);
  hipMemsetAsync(cursor, 0, N_NODESC * sizeof(int), stream);
  hipMemsetAsync(MSG, 0, 8 * NPs * sizeof(float), stream);

  k_hist<<<(N_EDGESC + 255) / 256, 256, 0, stream>>>(ei, deg);
  k_scan<<<1, 1024, 0, stream>>>(deg, row_start);
  k_scatter<<<(N_EDGESC + 255) / 256, 256, 0, stream>>>(ei, row_start, cursor, perm);
  k_sortseg<<<(N_NODESC + 255) / 256, 256, 0, stream>>>(perm, row_start);
  k_wprep<<<448, 256, 0, stream>>>(W1, W2, W3, TT);

  k_node_up<<<dim3(157, 5), 256, 0, stream>>>(nf, Wsc, Wu0, Wu1, NShi, NSlo, SU, VU);

  k_edge_fused<<<NBLK_TOT, 256, 0, stream>>>(NShi, NSlo, SU, VU, ef, len, ea, ei,
                                             perm, row_start, W1, b1, b2, TT,
                                             MSG, CONT);

  k_fixup<<<(N_NODESC * 32 + 255) / 256, 256, 0, stream>>>(MSG, CONT, row_start);
  k_out<<<dim3(157, 4), 256, 0, stream>>>(MSG, Wo0, Wo1, out);
}

// Round 7
// 412.291 us; speedup vs baseline: 12.5118x; 1.2317x over previous
//
#include <hip/hip_runtime.h>

#define N_NODESC 10000
#define N_EDGESC 160000
#define NBLK_TOT 2500                 // N_EDGESC/64
#define NP       (N_NODESC*128)       // plane size (floats)
#define INV128   0.08838834764831845f // 1/sqrt(128)
#define INV_SQRT3C 0.5773502691896258f
#define SCALE_OUT 0.00390625f         // (1/sqrt(256))/16

typedef __attribute__((ext_vector_type(8))) short bf16x8;
typedef __attribute__((ext_vector_type(4))) float f32x4;

__device__ __forceinline__ float silu_f(float x) {
  return x / (1.f + __expf(-x));
}
__device__ __forceinline__ ushort f2bf_rne(float x) {
  uint u = __float_as_uint(x);
  uint r = (u + 0x7FFFu + ((u >> 16) & 1u)) >> 16;
  return (ushort)r;
}
__device__ __forceinline__ float bf2f(ushort h) {
  return __uint_as_float(((uint)h) << 16);
}

// ---------------- CSR build ------------------------------------------------
__global__ __launch_bounds__(256) void k_hist(const int* __restrict__ eidx,
                                              int* __restrict__ deg) {
  int e = blockIdx.x * 256 + threadIdx.x;
  if (e < N_EDGESC) atomicAdd(&deg[eidx[N_EDGESC + e]], 1);
}

__global__ __launch_bounds__(1024) void k_scan(const int* __restrict__ deg,
                                               int* __restrict__ row_start) {
  __shared__ int buf[1024];
  const int t = threadIdx.x;
  int d[10];
  int loc = 0;
  #pragma unroll
  for (int i = 0; i < 10; i++) {
    int n = t * 10 + i;
    d[i] = (n < N_NODESC) ? deg[n] : 0;
    loc += d[i];
  }
  buf[t] = loc;
  __syncthreads();
  int v = loc;
  for (int off = 1; off < 1024; off <<= 1) {
    int u = (t >= off) ? buf[t - off] : 0;
    __syncthreads();
    v += u;
    buf[t] = v;
    __syncthreads();
  }
  int run = v - loc;
  #pragma unroll
  for (int i = 0; i < 10; i++) {
    int n = t * 10 + i;
    if (n < N_NODESC) row_start[n] = run;
    run += d[i];
  }
  if (t == 1023) row_start[N_NODESC] = v;
}

__global__ __launch_bounds__(256) void k_scatter(const int* __restrict__ eidx,
                                                 const int* __restrict__ row_start,
                                                 int* __restrict__ cursor,
                                                 int* __restrict__ perm) {
  int e = blockIdx.x * 256 + threadIdx.x;
  if (e < N_EDGESC) {
    int r = eidx[N_EDGESC + e];
    int pos = row_start[r] + atomicAdd(&cursor[r], 1);
    perm[pos] = e;
  }
}

__global__ __launch_bounds__(256) void k_sortseg(int* __restrict__ perm,
                                                 const int* __restrict__ row_start) {
  int n = blockIdx.x * 256 + threadIdx.x;
  if (n >= N_NODESC) return;
  int s = row_start[n], e = row_start[n + 1];
  for (int i = s + 1; i < e; i++) {
    int key = perm[i];
    int j = i - 1;
    while (j >= s && perm[j] > key) { perm[j + 1] = perm[j]; j--; }
    perm[j + 1] = key;
  }
}

// ---------------- weight prep: tile-linear staging buffer ------------------
// TT tiles (each [128 n][128 k] bf16, 32KB):
// t0-t3  W1 (k0.hi, k0.lo, k1.hi, k1.lo)
// t4-t5  W2 (hi, lo)
// t6-t9  W3 cb0..cb3 (hi only)
// t10-15 Wsc.hi/lo, Wu0.hi/lo, Wu1.hi/lo
// t16-23 Wo0 (k0.hi,k0.lo,k1.hi,k1.lo), Wo1 (same)
__global__ __launch_bounds__(256) void k_wprep(
    const float* __restrict__ W1, const float* __restrict__ W2,
    const float* __restrict__ W3,
    const float* __restrict__ Wsc, const float* __restrict__ Wu0,
    const float* __restrict__ Wu1,
    const float* __restrict__ Wo0, const float* __restrict__ Wo1,
    ushort* __restrict__ TT) {
  int id = blockIdx.x * 256 + threadIdx.x;
  if (id < 32768) {                   // W1: k 0..255, n 0..127
    int k = id >> 7, n = id & 127;
    float v = W1[k * 128 + n];
    int half = k >> 7, kk = k & 127;
    ushort hi = f2bf_rne(v);
    TT[(half * 2 + 0) * 16384 + n * 128 + kk] = hi;
    TT[(half * 2 + 1) * 16384 + n * 128 + kk] = f2bf_rne(v - bf2f(hi));
  } else if (id < 49152) {            // W2
    int t = id - 32768;
    int k = t >> 7, n = t & 127;
    float v = W2[k * 128 + n];
    ushort hi = f2bf_rne(v);
    TT[4 * 16384 + n * 128 + k] = hi;
    TT[5 * 16384 + n * 128 + k] = f2bf_rne(v - bf2f(hi));
  } else if (id < 114688) {           // W3 hi only
    int s = id - 49152;
    int k = s >> 9, col = s & 511;
    int cb = col >> 7, n = col & 127;
    TT[(6 + cb) * 16384 + n * 128 + k] = f2bf_rne(W3[k * 512 + col]);
  } else if (id < 163840) {           // Wsc/Wu0/Wu1 hi+lo
    int t = id - 114688;
    int w = t / 16384, r = t & 16383;
    int n = r >> 7, k = r & 127;
    const float* W = (w == 0) ? Wsc : ((w == 1) ? Wu0 : Wu1);
    float v = W[k * 128 + n];
    ushort hi = f2bf_rne(v);
    TT[(10 + w * 2) * 16384 + n * 128 + k] = hi;
    TT[(11 + w * 2) * 16384 + n * 128 + k] = f2bf_rne(v - bf2f(hi));
  } else if (id < 229376) {           // Wo0/Wo1 hi+lo, two k-halves
    int t = id - 163840;
    int w = t >> 15, r = t & 32767;
    int k = r >> 7, n = r & 127;
    const float* W = (w == 0) ? Wo0 : Wo1;
    float v = W[k * 128 + n];
    int kh = k >> 7, kk = k & 127;
    ushort hi = f2bf_rne(v);
    TT[(16 + w * 4 + kh * 2) * 16384 + n * 128 + kk] = hi;
    TT[(17 + w * 4 + kh * 2) * 16384 + n * 128 + kk] = f2bf_rne(v - bf2f(hi));
  }
}

// ---------------- shared GEMM macros (split-bf16 MFMA) ---------------------
#define GEMM_PASS2(ACC)                                                        \
  _Pragma("unroll") for (int s = 0; s < 4; s++) {                              \
    bf16x8 ah = *(const bf16x8*)&sAh[ar][s * 32 + lq * 8];                     \
    bf16x8 al = *(const bf16x8*)&sAl[ar][s * 32 + lq * 8];                     \
    _Pragma("unroll") for (int nt = 0; nt < 8; nt++) {                         \
      bf16x8 bb = *(const bf16x8*)&sB[nt * 16 + ln][s * 32 + lq * 8];          \
      ACC[nt] = __builtin_amdgcn_mfma_f32_16x16x32_bf16(ah, bb, ACC[nt], 0, 0, 0); \
      ACC[nt] = __builtin_amdgcn_mfma_f32_16x16x32_bf16(al, bb, ACC[nt], 0, 0, 0); \
    }                                                                          \
  }

#define GEMM_PASS1(ACC)                                                        \
  _Pragma("unroll") for (int s = 0; s < 4; s++) {                              \
    bf16x8 ah = *(const bf16x8*)&sAh[ar][s * 32 + lq * 8];                     \
    _Pragma("unroll") for (int nt = 0; nt < 8; nt++) {                         \
      bf16x8 bb = *(const bf16x8*)&sB[nt * 16 + ln][s * 32 + lq * 8];          \
      ACC[nt] = __builtin_amdgcn_mfma_f32_16x16x32_bf16(ah, bb, ACC[nt], 0, 0, 0); \
    }                                                                          \
  }

// transient staging: load whole tile to short-lived regs, write to LDS
#define STAGEB(T) { uint4 tv[8];                                               \
  _Pragma("unroll") for (int i = 0; i < 8; i++)                                \
    tv[i] = ttp[(T) * 2048 + cid + 256 * i];                                   \
  _Pragma("unroll") for (int i = 0; i < 8; i++) {                              \
    int c = cid + 256 * i;                                                     \
    *(uint4*)&sB[c >> 4][(c & 15) * 8] = tv[i]; } }

// ---------------- K1: node up-projections (MFMA) ---------------------------
__global__ __launch_bounds__(256, 2) void k_node_up(
    const float* __restrict__ nf,
    const ushort* __restrict__ TT,
    ushort* __restrict__ NShi,
    ushort* __restrict__ NSlo,
    float* __restrict__ SU,
    float* __restrict__ VU)
{
  __shared__ ushort sAh[64][136];
  __shared__ ushort sAl[64][136];
  __shared__ ushort sB[128][136];
  const int n0 = blockIdx.x * 64;
  const int which = blockIdx.y;  // 0 NS, 1 SU, 2..4 VU comp
  const int cid = threadIdx.x;
  const int wid = cid >> 6;
  const int lane = cid & 63;
  const int lq = lane >> 4;
  const int ln = lane & 15;
  const int ar = wid * 16 + ln;
  const uint4* ttp = (const uint4*)TT;
  const int tile = (which == 0) ? 10 : ((which == 1) ? 12 : 14);

  // stage A (f32 -> hi/lo bf16 in LDS)
  if (which < 2) {
    for (int idx = cid; idx < 64 * 32; idx += 256) {
      int r = idx >> 5, fc = (idx & 31) << 2;
      int n = n0 + r;
      float4 v = {0.f, 0.f, 0.f, 0.f};
      if (n < N_NODESC) v = *(const float4*)&nf[(size_t)n * 512 + fc];
      float vv[4] = {v.x, v.y, v.z, v.w};
      #pragma unroll
      for (int j = 0; j < 4; j++) {
        ushort hi = f2bf_rne(vv[j]);
        sAh[r][fc + j] = hi;
        sAl[r][fc + j] = f2bf_rne(vv[j] - bf2f(hi));
      }
    }
  } else {
    int comp = which - 2;
    for (int idx = cid; idx < 64 * 128; idx += 256) {
      int r = idx >> 7, u = idx & 127;
      int n = n0 + r;
      float v = (n < N_NODESC) ? nf[(size_t)n * 512 + 128 + u * 3 + comp] : 0.f;
      ushort hi = f2bf_rne(v);
      sAh[r][u] = hi;
      sAl[r][u] = f2bf_rne(v - bf2f(hi));
    }
  }
  STAGEB(tile)
  __syncthreads();
  f32x4 acc[8];
  #pragma unroll
  for (int nt = 0; nt < 8; nt++) acc[nt] = (f32x4){0.f, 0.f, 0.f, 0.f};
  GEMM_PASS2(acc)
  __syncthreads();
  STAGEB(tile + 1)
  __syncthreads();
  GEMM_PASS1(acc)

  #pragma unroll
  for (int q = 0; q < 4; q++) {
    int n = n0 + wid * 16 + lq * 4 + q;
    if (n < N_NODESC) {
      #pragma unroll
      for (int nt = 0; nt < 8; nt++) {
        int col = nt * 16 + ln;
        float o = acc[nt][q] * INV128;
        if (which == 0) {
          ushort hi = f2bf_rne(o);
          NShi[(size_t)n * 128 + col] = hi;
          NSlo[(size_t)n * 128 + col] = f2bf_rne(o - bf2f(hi));
        } else if (which == 1) {
          SU[(size_t)n * 128 + col] = o;
        } else {
          VU[(size_t)(which - 2) * NP + (size_t)n * 128 + col] = o;
        }
      }
    }
  }
}

// ---------------- fused edge kernel (MFMA split-bf16) ----------------------
#define STAGEA(USE_RCV)                                                        \
  for (int c = cid; c < 64 * 16; c += 256) {                                   \
    int r = c >> 4, o = c & 15;                                                \
    int n = (USE_RCV) ? sRcv[r] : sSnd[r];                                     \
    *(uint4*)&sAh[r][o * 8] = *(const uint4*)&NShi[(size_t)n * 128 + o * 8];   \
    *(uint4*)&sAl[r][o * 8] = *(const uint4*)&NSlo[(size_t)n * 128 + o * 8];   \
  }

// parallel segmented reduce: tasks = nseg x 128 cols, 8-batched loads,
// sequential ascending adds within segment (deterministic).
#define REDUCE(P, MI) {                                                        \
  const int nseg128 = sNseg << 7;                                              \
  for (int task = cid; task < nseg128; task += 256) {                          \
    const int si = task >> 7, col = task & 127;                                \
    const int s = sSegStart[si], e = sSegStart[si + 1];                        \
    float sum = 0.f;                                                           \
    int e2 = s;                                                                \
    for (; e2 + 8 <= e; e2 += 8) {                                             \
      float m0 = sMsg[e2][col],     m1 = sMsg[e2 + 1][col];                    \
      float m2 = sMsg[e2 + 2][col], m3 = sMsg[e2 + 3][col];                    \
      float m4 = sMsg[e2 + 4][col], m5 = sMsg[e2 + 5][col];                    \
      float m6 = sMsg[e2 + 6][col], m7 = sMsg[e2 + 7][col];                    \
      if ((MI) >= 0) {                                                         \
        const int mi = (MI) >= 0 ? (MI) : 0;                                   \
        sum += m0 * sY4[e2][mi];     sum += m1 * sY4[e2 + 1][mi];              \
        sum += m2 * sY4[e2 + 2][mi]; sum += m3 * sY4[e2 + 3][mi];              \
        sum += m4 * sY4[e2 + 4][mi]; sum += m5 * sY4[e2 + 5][mi];              \
        sum += m6 * sY4[e2 + 6][mi]; sum += m7 * sY4[e2 + 7][mi];              \
      } else { sum += m0; sum += m1; sum += m2; sum += m3;                     \
               sum += m4; sum += m5; sum += m6; sum += m7; }                   \
    }                                                                          \
    for (; e2 < e; e2++) {                                                     \
      float mv = sMsg[e2][col];                                                \
      sum += ((MI) >= 0) ? mv * sY4[e2][(MI) >= 0 ? (MI) : 0] : mv;            \
    }                                                                          \
    if (si == 0 && contF)                                                      \
      CONT[(size_t)gblk * 1024 + (P) * 128 + col] = sum;                       \
    else                                                                       \
      MSG[(size_t)(P) * NP + (size_t)sRcv[s] * 128 + col] = sum;               \
  } }

__global__ __launch_bounds__(256, 2) void k_edge_fused(
    const ushort* __restrict__ NShi,
    const ushort* __restrict__ NSlo,
    const float* __restrict__ SU,
    const float* __restrict__ VU,   // 3 planes
    const float* __restrict__ ef,
    const float* __restrict__ len,
    const float* __restrict__ ea,
    const int* __restrict__ eidx,
    const int* __restrict__ perm,
    const int* __restrict__ row_start,
    const float* __restrict__ W1,   // f32, for tail rows
    const float* __restrict__ b1,
    const float* __restrict__ b2,
    const ushort* __restrict__ TT,
    float* __restrict__ MSG,        // 8 planes
    float* __restrict__ CONT)       // [NBLK_TOT][1024]
{
  __shared__ ushort sAh[64][136];
  __shared__ ushort sAl[64][136];
  __shared__ ushort sB[128][136];   // W tile during GEMM; f32 msg buffer in emit
  __shared__ float sT[11][128];     // W1 tail rows (9), b1, b2
  __shared__ float sEL[64][10];
  __shared__ float sY4[64][4];
  __shared__ int sSnd[64], sRcv[64];
  __shared__ int sSegStart[65];
  __shared__ int sNseg;
  __shared__ int sContFirst;
  float (*sMsg)[132] = (float (*)[132])&sB[0][0];

  const int gblk = blockIdx.x;
  const int j0 = gblk * 64;
  const int cid = threadIdx.x;
  const int wid = cid >> 6;
  const int lane = cid & 63;
  const int lq = lane >> 4;
  const int ln = lane & 15;
  const int ar = wid * 16 + ln;
  const uint4* ttp = (const uint4*)TT;

  if (cid < 64) {
    int r = cid;
    int e = perm[j0 + r];
    sSnd[r] = eidx[e];
    sRcv[r] = eidx[N_EDGESC + e];
    #pragma unroll
    for (int q = 0; q < 8; q++) sEL[r][q] = ef[(size_t)e * 8 + q];
    sEL[r][8] = len[e];
    *(float4*)&sY4[r][0] = *(const float4*)&ea[(size_t)e * 4];
    if (r == 0) sContFirst = (row_start[eidx[N_EDGESC + e]] != j0) ? 1 : 0;
  }
  for (int idx = cid; idx < 11 * 128; idx += 256) {
    int r = idx >> 7, c2 = idx & 127;
    sT[r][c2] = (r < 9) ? W1[(256 + r) * 128 + c2] : (r == 9 ? b1[c2] : b2[c2]);
  }
  __syncthreads();                       // B1: meta + sT
  const bool contF = (sContFirst != 0);

  // segment list via wave ballot (wave 0 only; lanes = edges)
  if (cid < 64) {
    int r = cid;
    bool flag = (r == 0) || (sRcv[r] != sRcv[r - 1]);
    unsigned long long mask = __ballot(flag ? 1 : 0);
    if (flag) {
      int rank = __popcll(mask & ((1ull << r) - 1ull));
      sSegStart[rank] = r;
    }
    if (r == 0) sNseg = __popcll(mask);
    if (r == 63) sSegStart[__popcll(mask)] = 64;
  }

  // ---------- layer 1 (K=256 as two 128-halves, 3-term split) ----------
  f32x4 acc[8];
  #pragma unroll
  for (int nt = 0; nt < 8; nt++) acc[nt] = (f32x4){0.f, 0.f, 0.f, 0.f};

  STAGEA(0)
  STAGEB(0)
  __syncthreads();
  GEMM_PASS2(acc)
  __syncthreads();
  STAGEB(1)
  __syncthreads();
  GEMM_PASS1(acc)
  __syncthreads();
  STAGEA(1)
  STAGEB(2)
  __syncthreads();
  GEMM_PASS2(acc)
  __syncthreads();
  STAGEB(3)
  __syncthreads();
  GEMM_PASS1(acc)
  __syncthreads();

  // tail + bias + silu -> h1 (bf16 hi/lo into sAh/sAl)
  #pragma unroll
  for (int q = 0; q < 4; q++) {
    int rr = wid * 16 + lq * 4 + q;
    float el[9];
    #pragma unroll
    for (int t = 0; t < 9; t++) el[t] = sEL[rr][t];
    #pragma unroll
    for (int nt = 0; nt < 8; nt++) {
      int col = nt * 16 + ln;
      float v = acc[nt][q] + sT[9][col];
      #pragma unroll
      for (int t = 0; t < 9; t++) v += el[t] * sT[t][col];
      float h = silu_f(v);
      ushort hi = f2bf_rne(h);
      sAh[rr][col] = hi;
      sAl[rr][col] = f2bf_rne(h - bf2f(hi));
    }
  }
  STAGEB(4)
  __syncthreads();

  // ---------- layer 2 ----------
  f32x4 acc2[8];
  #pragma unroll
  for (int nt = 0; nt < 8; nt++) acc2[nt] = (f32x4){0.f, 0.f, 0.f, 0.f};
  GEMM_PASS2(acc2)
  __syncthreads();
  STAGEB(5)
  __syncthreads();
  GEMM_PASS1(acc2)
  __syncthreads();
  #pragma unroll
  for (int q = 0; q < 4; q++) {
    int rr = wid * 16 + lq * 4 + q;
    #pragma unroll
    for (int nt = 0; nt < 8; nt++) {
      int col = nt * 16 + ln;
      float h = silu_f(acc2[nt][q] + sT[10][col]);
      ushort hi = f2bf_rne(h);
      sAh[rr][col] = hi;
      sAl[rr][col] = f2bf_rne(h - bf2f(hi));
    }
  }

  // layer-3 preamble + se gather hoisted here: latency hides under
  // STAGEB(6) + cb0 GEMM
  int erow[4], esnd[4];
  float y0r[4], y1r3[4][3];
  #pragma unroll
  for (int q = 0; q < 4; q++) {
    int rr = wid * 16 + lq * 4 + q;
    erow[q] = rr;
    esnd[q] = sSnd[rr];
    y0r[q] = sY4[rr][0];
    #pragma unroll
    for (int i = 0; i < 3; i++) y1r3[q][i] = sY4[rr][1 + i];
  }
  float se[4][8];
  #pragma unroll
  for (int q = 0; q < 4; q++)
    #pragma unroll
    for (int nt = 0; nt < 8; nt++)
      se[q][nt] = SU[(size_t)esnd[q] * 128 + nt * 16 + ln];
  float dacc[4][8];

  STAGEB(6)
  __syncthreads();

  // ----- cb0 (tile t6) -----
  {
    f32x4 acc3[8];
    #pragma unroll
    for (int nt = 0; nt < 8; nt++) acc3[nt] = (f32x4){0.f, 0.f, 0.f, 0.f};
    GEMM_PASS2(acc3)
    __syncthreads();                     // sB free -> sMsg
    #pragma unroll
    for (int q = 0; q < 4; q++)
      #pragma unroll
      for (int nt = 0; nt < 8; nt++)
        sMsg[erow[q]][nt * 16 + ln] = acc3[nt][q] * se[q][nt] * y0r[q];
    __syncthreads();
    REDUCE(0, -1)
    __syncthreads();
    STAGEB(7)
    __syncthreads();
  }
  // ----- cb1 (tile t7) -----
  {
    f32x4 acc3[8];
    #pragma unroll
    for (int nt = 0; nt < 8; nt++) acc3[nt] = (f32x4){0.f, 0.f, 0.f, 0.f};
    GEMM_PASS2(acc3)
    __syncthreads();
    #pragma unroll
    for (int q = 0; q < 4; q++)
      #pragma unroll
      for (int nt = 0; nt < 8; nt++)
        sMsg[erow[q]][nt * 16 + ln] = acc3[nt][q] * se[q][nt];
    __syncthreads();
    REDUCE(2, 1)
    REDUCE(3, 2)
    REDUCE(4, 3)
    __syncthreads();
    STAGEB(8)
    __syncthreads();
  }
  // ----- cb2 (tile t8) -----
  {
    f32x4 acc3[8];
    #pragma unroll
    for (int nt = 0; nt < 8; nt++) acc3[nt] = (f32x4){0.f, 0.f, 0.f, 0.f};
    GEMM_PASS2(acc3)
    __syncthreads();
    for (int pi = 0; pi < 3; pi++) {
      float vu[4][8];
      #pragma unroll
      for (int q = 0; q < 4; q++)
        #pragma unroll
        for (int nt = 0; nt < 8; nt++) {
          vu[q][nt] = VU[(size_t)pi * NP + (size_t)esnd[q] * 128 + nt * 16 + ln];
          if (pi == 0) dacc[q][nt] = vu[q][nt] * y1r3[q][0];
          else dacc[q][nt] += vu[q][nt] * y1r3[q][pi];
        }
      #pragma unroll
      for (int q = 0; q < 4; q++)
        #pragma unroll
        for (int nt = 0; nt < 8; nt++)
          sMsg[erow[q]][nt * 16 + ln] = acc3[nt][q] * vu[q][nt];
      __syncthreads();
      if (pi == 0) { REDUCE(5, 0) }
      else if (pi == 1) { REDUCE(6, 0) }
      else { REDUCE(7, 0) }
      __syncthreads();
    }
    STAGEB(9)
    __syncthreads();
  }
  // ----- cb3 (tile t9) -----
  {
    f32x4 acc3[8];
    #pragma unroll
    for (int nt = 0; nt < 8; nt++) acc3[nt] = (f32x4){0.f, 0.f, 0.f, 0.f};
    GEMM_PASS2(acc3)
    __syncthreads();
    #pragma unroll
    for (int q = 0; q < 4; q++)
      #pragma unroll
      for (int nt = 0; nt < 8; nt++)
        sMsg[erow[q]][nt * 16 + ln] = acc3[nt][q] * dacc[q][nt] * INV_SQRT3C;
    __syncthreads();
    REDUCE(1, -1)
  }
}

// ---------------- fixup: add continuation partials into MSG ----------------
__global__ __launch_bounds__(256) void k_fixup(float* __restrict__ MSG,
                                               const float* __restrict__ CONT,
                                               const int* __restrict__ row_start) {
  int t = blockIdx.x * 256 + threadIdx.x;
  int n = t >> 5;
  int c4 = (t & 31) * 4;
  if (n >= N_NODESC) return;
  int s = row_start[n], e = row_start[n + 1];
  if (e <= s) return;
  int b0 = s >> 6, b1 = (e - 1) >> 6;
  if (b1 <= b0) return;
  for (int p = 0; p < 8; p++) {
    float4 v = *(float4*)&MSG[(size_t)p * NP + (size_t)n * 128 + c4];
    for (int b = b0 + 1; b <= b1; b++) {
      const float4 u = *(const float4*)&CONT[(size_t)b * 1024 + p * 128 + c4];
      v.x += u.x; v.y += u.y; v.z += u.z; v.w += u.w;
    }
    *(float4*)&MSG[(size_t)p * NP + (size_t)n * 128 + c4] = v;
  }
}

// ---------------- K4: output GEMMs (MFMA) ----------------------------------
__global__ __launch_bounds__(256, 2) void k_out(
    const float* __restrict__ MSG,
    const ushort* __restrict__ TT,
    float* __restrict__ out)
{
  __shared__ ushort sAh[64][136];
  __shared__ ushort sAl[64][136];
  __shared__ ushort sB[128][136];
  const int n0 = blockIdx.x * 64;
  const int y = blockIdx.y;
  const int cid = threadIdx.x;
  const int wid = cid >> 6;
  const int lane = cid & 63;
  const int lq = lane >> 4;
  const int ln = lane & 15;
  const int ar = wid * 16 + ln;
  const uint4* ttp = (const uint4*)TT;
  const int pA = (y == 0) ? 0 : (1 + y);
  const int pB = (y == 0) ? 1 : (4 + y);
  const int tbase = 16 + ((y == 0) ? 0 : 4);

  f32x4 acc[8];
  #pragma unroll
  for (int nt = 0; nt < 8; nt++) acc[nt] = (f32x4){0.f, 0.f, 0.f, 0.f};

  for (int kh = 0; kh < 2; kh++) {
    if (kh) __syncthreads();             // protect previous PASS1 reads
    const int p = kh ? pB : pA;
    for (int idx = cid; idx < 64 * 32; idx += 256) {
      int r = idx >> 5, fc = (idx & 31) << 2;
      int n = n0 + r;
      float4 v = {0.f, 0.f, 0.f, 0.f};
      if (n < N_NODESC) v = *(const float4*)&MSG[(size_t)p * NP + (size_t)n * 128 + fc];
      float vv[4] = {v.x, v.y, v.z, v.w};
      #pragma unroll
      for (int j = 0; j < 4; j++) {
        ushort hi = f2bf_rne(vv[j]);
        sAh[r][fc + j] = hi;
        sAl[r][fc + j] = f2bf_rne(vv[j] - bf2f(hi));
      }
    }
    STAGEB(tbase + kh * 2)
    __syncthreads();
    GEMM_PASS2(acc)
    __syncthreads();
    STAGEB(tbase + kh * 2 + 1)
    __syncthreads();
    GEMM_PASS1(acc)
  }
  #pragma unroll
  for (int q = 0; q < 4; q++) {
    int n = n0 + wid * 16 + lq * 4 + q;
    if (n < N_NODESC) {
      #pragma unroll
      for (int nt = 0; nt < 8; nt++)
        out[(size_t)n * 512 + (size_t)(nt * 16 + ln) * 4 + y] = acc[nt][q] * SCALE_OUT;
    }
  }
}

extern "C" void kernel_launch(void* const* d_in, const int* in_sizes, int n_in,
                              void* d_out, int out_size, void* d_ws, size_t ws_size,
                              hipStream_t stream) {
  const float* nf  = (const float*)d_in[0];
  const float* ea  = (const float*)d_in[1];
  const float* ef  = (const float*)d_in[2];
  const float* len = (const float*)d_in[3];
  const int*   ei  = (const int*)d_in[4];
  const float* Wsc = (const float*)d_in[5];
  const float* Wu0 = (const float*)d_in[6];
  const float* Wu1 = (const float*)d_in[7];
  const float* W1  = (const float*)d_in[8];
  const float* b1  = (const float*)d_in[9];
  const float* W2  = (const float*)d_in[10];
  const float* b2  = (const float*)d_in[11];
  const float* W3  = (const float*)d_in[12];
  const float* Wo0 = (const float*)d_in[13];
  const float* Wo1 = (const float*)d_in[14];
  float* out = (float*)d_out;
  float* ws  = (float*)d_ws;

  const size_t NPs = (size_t)NP;
  float* SU   = ws;                            // 1 plane
  float* VU   = ws + NPs;                      // 3 planes
  float* MSG  = ws + 4 * NPs;                  // 8 planes
  float* CONT = ws + 12 * NPs;                 // NBLK_TOT*1024
  ushort* NShi = (ushort*)(CONT + (size_t)NBLK_TOT * 1024);
  ushort* NSlo = NShi + NPs;
  ushort* TT   = NSlo + NPs;                   // 24*16384 ushorts
  int* perm      = (int*)(TT + 24 * 16384);
  int* deg       = perm + N_EDGESC;
  int* cursor    = deg + N_NODESC;
  int* row_start = cursor + N_NODESC;          // N_NODESC+1 ints

  hipMemsetAsync(deg, 0, N_NODESC * sizeof(int), stream);
  hipMemsetAsync(cursor, 0, N_NODESC * sizeof(int), stream);
  hipMemsetAsync(MSG, 0, 8 * NPs * sizeof(float), stream);

  k_hist<<<(N_EDGESC + 255) / 256, 256, 0, stream>>>(ei, deg);
  k_scan<<<1, 1024, 0, stream>>>(deg, row_start);
  k_scatter<<<(N_EDGESC + 255) / 256, 256, 0, stream>>>(ei, row_start, cursor, perm);
  k_sortseg<<<(N_NODESC + 255) / 256, 256, 0, stream>>>(perm, row_start);
  k_wprep<<<896, 256, 0, stream>>>(W1, W2, W3, Wsc, Wu0, Wu1, Wo0, Wo1, TT);

  k_node_up<<<dim3(157, 5), 256, 0, stream>>>(nf, TT, NShi, NSlo, SU, VU);

  k_edge_fused<<<NBLK_TOT, 256, 0, stream>>>(NShi, NSlo, SU, VU, ef, len, ea, ei,
                                             perm, row_start, W1, b1, b2, TT,
                                             MSG, CONT);

  k_fixup<<<(N_NODESC * 32 + 255) / 256, 256, 0, stream>>>(MSG, CONT, row_start);
  k_out<<<dim3(157, 4), 256, 0, stream>>>(MSG, TT, out);
}